// Round 6
// baseline (1307.774 us; speedup 1.0000x reference)
//
#include <hip/hip_runtime.h>
#include <hip/hip_bf16.h>

#define T_TOK 8192
#define DDIM 1024
#define HDIM 4096

typedef __bf16 bf16;
typedef bf16 bf16x8 __attribute__((ext_vector_type(8)));
typedef float f32x4 __attribute__((ext_vector_type(4)));

#define ASM_VMCNT(n) asm volatile("s_waitcnt vmcnt(" #n ")" ::: "memory")
#define MFMA16(a, b, c) __builtin_amdgcn_mfma_f32_16x16x32_bf16((a), (b), (c), 0, 0, 0)

__device__ __forceinline__ void gl_lds16(const void* g, void* l) {
  __builtin_amdgcn_global_load_lds(
      (const __attribute__((address_space(1))) unsigned int*)g,
      (__attribute__((address_space(3))) unsigned int*)l, 16, 0, 0);
}

// ---------------- x fp32 -> bf16 ----------------
__global__ __launch_bounds__(256) void convert_x(const float* __restrict__ x,
                                                 bf16* __restrict__ xb) {
  const size_t i = ((size_t)blockIdx.x * 256 + threadIdx.x) * 8;
  const float4 v0 = *(const float4*)(x + i);
  const float4 v1 = *(const float4*)(x + i + 4);
  bf16x8 o;
  o[0] = (bf16)v0.x; o[1] = (bf16)v0.y; o[2] = (bf16)v0.z; o[3] = (bf16)v0.w;
  o[4] = (bf16)v1.x; o[5] = (bf16)v1.y; o[6] = (bf16)v1.z; o[7] = (bf16)v1.w;
  *(bf16x8*)(xb + i) = o;
}

// ---------------- weight transpose + convert: src [R,C] f32 -> dst [C,R] bf16
__global__ __launch_bounds__(256) void transpose_convert(
    const float* __restrict__ src, bf16* __restrict__ dst, int R, int C) {
  __shared__ float tile[32][33];
  const size_t mat = (size_t)blockIdx.z * R * C;
  const int c0 = blockIdx.x * 32, r0 = blockIdx.y * 32;
  const int tx = threadIdx.x & 31, ty = threadIdx.x >> 5;  // 32 x 8
#pragma unroll
  for (int i = 0; i < 4; ++i)
    tile[ty + 8 * i][tx] =
        src[mat + (size_t)(r0 + ty + 8 * i) * C + c0 + tx];
  __syncthreads();
#pragma unroll
  for (int i = 0; i < 4; ++i)
    dst[mat + (size_t)(c0 + ty + 8 * i) * R + r0 + tx] =
        (bf16)tile[tx][ty + 8 * i];
}

// ---------------- router: softmax/top2/gates + aux + expert token lists ----
__global__ __launch_bounds__(256) void router_kernel(
    const float* __restrict__ x, const float* __restrict__ srw,
    const float* __restrict__ srb, const float* __restrict__ hrw,
    const float* __restrict__ hrb, float* __restrict__ gate,
    float* __restrict__ auxg, int* __restrict__ cnt, int* __restrict__ lists) {
  __shared__ float saux[8];
  if (threadIdx.x < 8) saux[threadIdx.x] = 0.0f;
  __syncthreads();

  const int lane = threadIdx.x & 63;
  const int w = threadIdx.x >> 6;
  const int t = blockIdx.x * 4 + w;

  const float* xr = x + (size_t)t * DDIM;
  float p0 = 0, p1 = 0, p2 = 0, p3 = 0, p4 = 0, p5 = 0;
#pragma unroll
  for (int c = 0; c < 4; ++c) {
    const int d = c * 256 + lane * 4;
    const float4 xv = *(const float4*)(xr + d);
    const float xa[4] = {xv.x, xv.y, xv.z, xv.w};
#pragma unroll
    for (int j = 0; j < 4; ++j) {
      const float xd = xa[j];
      const float4 r4 = *(const float4*)(srw + (size_t)(d + j) * 4);
      p0 += xd * r4.x; p1 += xd * r4.y; p2 += xd * r4.z; p3 += xd * r4.w;
      const float2 r2 = *(const float2*)(hrw + (size_t)(d + j) * 2);
      p4 += xd * r2.x; p5 += xd * r2.y;
    }
  }
#pragma unroll
  for (int off = 32; off >= 1; off >>= 1) {
    p0 += __shfl_xor(p0, off);
    p1 += __shfl_xor(p1, off);
    p2 += __shfl_xor(p2, off);
    p3 += __shfl_xor(p3, off);
    p4 += __shfl_xor(p4, off);
    p5 += __shfl_xor(p5, off);
  }
  if (lane == 0) {
    const float l0 = p0 + srb[0], l1 = p1 + srb[1];
    const float l2 = p2 + srb[2], l3 = p3 + srb[3];
    const float m = fmaxf(fmaxf(l0, l1), fmaxf(l2, l3));
    const float e0 = expf(l0 - m), e1 = expf(l1 - m);
    const float e2 = expf(l2 - m), e3 = expf(l3 - m);
    const float s = e0 + e1 + e2 + e3;
    float pr[4] = {e0 / s, e1 / s, e2 / s, e3 / s};
    int i1 = 0; float v1 = pr[0];
#pragma unroll
    for (int e = 1; e < 4; ++e) if (pr[e] > v1) { v1 = pr[e]; i1 = e; }
    int i2 = -1; float v2 = -1.0f;
#pragma unroll
    for (int e = 0; e < 4; ++e)
      if (e != i1 && pr[e] > v2) { v2 = pr[e]; i2 = e; }
    float g[4] = {0, 0, 0, 0};
    g[i1] = v1; g[i2] = v2;
    float* gr = gate + (size_t)t * 8;
    gr[0] = g[0]; gr[1] = g[1]; gr[2] = g[2]; gr[3] = g[3];
    const float h0 = p4 + hrb[0], h1 = p5 + hrb[1];
    const float mh = fmaxf(h0, h1);
    const float q0 = expf(h0 - mh), q1 = expf(h1 - mh);
    const float qs = q0 + q1;
    gr[4] = q0 / qs; gr[5] = q1 / qs; gr[6] = 0; gr[7] = 0;
    // expert token lists (order-independent numerically)
    const int s1 = atomicAdd(&cnt[i1], 1);
    lists[i1 * 8192 + s1] = t;
    const int s2 = atomicAdd(&cnt[i2], 1);
    lists[i2 * 8192 + s2] = t;
    atomicAdd(&saux[i1], 1.0f);
    atomicAdd(&saux[i2], 1.0f);
    atomicAdd(&saux[4 + 0], pr[0]);
    atomicAdd(&saux[4 + 1], pr[1]);
    atomicAdd(&saux[4 + 2], pr[2]);
    atomicAdd(&saux[4 + 3], pr[3]);
  }
  __syncthreads();
  if (threadIdx.x < 8) atomicAdd(&auxg[threadIdx.x], saux[threadIdx.x]);
}

__global__ void aux_finalize(const float* __restrict__ auxg,
                             float* __restrict__ outp) {
  float a = 0.0f;
#pragma unroll
  for (int e = 0; e < 4; ++e)
    a += (auxg[e] / (float)(T_TOK * 2)) * (auxg[4 + e] / (float)T_TOK);
  outp[0] = 4.0f * a;
}

// ---------------- 4-phase pipelined GEMM  C = A[M,K]*B[N,K]^T ----------------
// BM=256, BK=64, 8 waves (2Mx4N), 2-deep LDS dbuf, counted vmcnt (6/4),
// swizzle byte ^= ((row&7)<<4) in 128B rows (pre-swizzled global src + read).
// Race-safe staging: every overwritten LDS chunk was consumed >=1 barrier ago.
// MODE 0: dense A, Hout = gelu(C+bias)                (shared gemm1)
// MODE 4: gathered A via lists[eid], Hout = gelu      (spec gemm1)
// MODE 1: dense, Fout[row] += gate[row*8+gidx]*(C+b)  (shared gemm2)
// MODE 3: scatter, Fout[tok] += gate[tok*8+gidx]*(C+b) (spec gemm2)
template <int BN_, int MODE>
__global__ __launch_bounds__(512, 2) void gemm4p(
    const bf16* __restrict__ A, const bf16* __restrict__ B, int M, int N,
    int K, const float* __restrict__ bias, bf16* __restrict__ Hout,
    float* __restrict__ Fout, const float* __restrict__ gate, int gidx,
    int NBn, int CH_M, int CH_N, const int* __restrict__ cnt,
    const int* __restrict__ lists, int eid) {
  constexpr int NREP = BN_ / 64;   // 4 (BN256) / 2 (BN128)
  constexpr int NHF = NREP / 2;
  constexpr int WNT = BN_ / 4;
  constexpr int ABYTES = 256 * 64 * 2;
  constexpr int BBYTES = BN_ * 64 * 2;
  constexpr bool DYN = (MODE == 3 || MODE == 4);

  __shared__ __align__(1024) bf16 Alds[2 * 256 * 64];
  __shared__ __align__(1024) bf16 Blds[2 * BN_ * 64];

  const int tid = threadIdx.x;
  const int lane = tid & 63, wid = tid >> 6;
  const int wm = wid >> 2, wn = wid & 3;
  const int lr = lane & 15, lg = lane >> 4;

  int bm, bn;
  if constexpr (DYN) {
    const int Mp = (cnt[eid] + 255) & ~255;
    const int live = (Mp >> 8) * NBn;
    const int ord = blockIdx.x;
    if (ord >= live) return;
    const int q = live >> 3, r = live & 7, xc = ord & 7;
    const int base = xc < r ? xc * (q + 1) : r * (q + 1) + (xc - r) * q;
    const int wg = base + (ord >> 3);
    bm = wg / NBn; bn = wg % NBn;
  } else {
    const int xcd = blockIdx.x & 7;
    const int idx = blockIdx.x >> 3;
    const int ncn = NBn / CH_N;
    const int cm = xcd / ncn, cn = xcd % ncn;
    bm = cm * CH_M + idx / CH_N;
    bn = cn * CH_N + idx % CH_N;
  }

  const int NT = K >> 6;

  // ---- staging source (pre-swizzled global, linear LDS dest) ----
  const int L = tid * 16;
  const int rl = L >> 7;                         // row 0..63 within 8KB chunk
  const int colb = (L & 127) ^ ((rl & 7) << 4);  // swizzled col byte

  int ar0 = bm * 256 + rl, ar1 = ar0 + 64, ar2 = ar0 + 128, ar3 = ar0 + 192;
  if constexpr (MODE == 4) {
    const int* lp = lists + eid * 8192;
    int t;
    t = lp[ar0]; ar0 = t < 0 ? 0 : t;
    t = lp[ar1]; ar1 = t < 0 ? 0 : t;
    t = lp[ar2]; ar2 = t < 0 ? 0 : t;
    t = lp[ar3]; ar3 = t < 0 ? 0 : t;
  }
  const bf16* sAc0 = A + (size_t)ar0 * K + (colb >> 1);
  const bf16* sAc1 = A + (size_t)ar1 * K + (colb >> 1);
  const bf16* sAc2 = A + (size_t)ar2 * K + (colb >> 1);
  const bf16* sAc3 = A + (size_t)ar3 * K + (colb >> 1);
  const bf16* sB = B + (size_t)(bn * BN_ + rl) * K + (colb >> 1);

  char* const ldsA = (char*)Alds;
  char* const ldsB = (char*)Blds;
  const int wb = wid * 1024;
  char* const stA[2] = {ldsA + wb, ldsA + ABYTES + wb};
  char* const stB[2] = {ldsB + wb, ldsB + BBYTES + wb};

  // ---- ds_read bases: ks0/ks1 per dbuf slot ----
  const int ax0 = (lg * 16) ^ ((lr & 7) << 4);
  const int ax1 = ax0 ^ 64;
  const int aro = (wm * 128 + lr) * 128;
  const int bro = (wn * WNT + lr) * 128;
  const char* const Ak0[2] = {ldsA + aro + ax0, ldsA + ABYTES + aro + ax0};
  const char* const Ak1[2] = {ldsA + aro + ax1, ldsA + ABYTES + aro + ax1};
  const char* const Bk0[2] = {ldsB + bro + ax0, ldsB + BBYTES + bro + ax0};
  const char* const Bk1[2] = {ldsB + bro + ax1, ldsB + BBYTES + bro + ax1};

  f32x4 acc[8][NREP] = {};

  // ---- prologue: T0 full, then T1 {B h0, B h1, A h0} ----
  gl_lds16(sAc0, stA[0]);
  gl_lds16(sAc1, stA[0] + 8192);
  gl_lds16(sAc2, stA[0] + 16384);
  gl_lds16(sAc3, stA[0] + 24576);
  gl_lds16(sB, stB[0]);
  gl_lds16(sB + (size_t)64 * K, stB[0] + 8192);
  if constexpr (BN_ == 256) {
    gl_lds16(sB + (size_t)128 * K, stB[0] + 16384);
    gl_lds16(sB + (size_t)192 * K, stB[0] + 24576);
  }
  gl_lds16(sB + 64, stB[1]);
  gl_lds16(sB + (size_t)64 * K + 64, stB[1] + 8192);
  if constexpr (BN_ == 256) {
    gl_lds16(sB + (size_t)128 * K + 64, stB[1] + 16384);
    gl_lds16(sB + (size_t)192 * K + 64, stB[1] + 24576);
  }
  gl_lds16(sAc0 + 64, stA[1]);
  gl_lds16(sAc1 + 64, stA[1] + 8192);
  if constexpr (BN_ == 256) ASM_VMCNT(6); else ASM_VMCNT(4);
  __builtin_amdgcn_s_barrier();

  for (int kt0 = 0; kt0 < NT; kt0 += 2) {
#pragma unroll
    for (int par = 0; par < 2; ++par) {
      const int kt = kt0 + par;
      const int cur = par, oth = par ^ 1;
      const bool st1 = (kt + 1) < NT, st2 = (kt + 2) < NT;
      const size_t ko1 = (size_t)(kt + 1) << 6, ko2 = (size_t)(kt + 2) << 6;
      const char* Ac0 = Ak0[cur]; const char* Ac1 = Ak1[cur];
      const char* Bc0 = Bk0[cur]; const char* Bc1 = Bk1[cur];

      bf16x8 af[4][2], bfr[NREP][2];

      // ---- phase 1: ds A(mh0)+B(nh0); stage A(kt+1)h1 -> oth ----
#pragma unroll
      for (int mf = 0; mf < 4; ++mf) {
        af[mf][0] = *(const bf16x8*)(Ac0 + mf * 2048);
        af[mf][1] = *(const bf16x8*)(Ac1 + mf * 2048);
      }
#pragma unroll
      for (int nf = 0; nf < NHF; ++nf) {
        bfr[nf][0] = *(const bf16x8*)(Bc0 + nf * 2048);
        bfr[nf][1] = *(const bf16x8*)(Bc1 + nf * 2048);
      }
      if (st1) {
        gl_lds16(sAc2 + ko1, stA[oth] + 16384);
        gl_lds16(sAc3 + ko1, stA[oth] + 24576);
      }
      __builtin_amdgcn_s_barrier();
      asm volatile("s_waitcnt lgkmcnt(0)" ::: "memory");
      __builtin_amdgcn_sched_barrier(0);
      __builtin_amdgcn_s_setprio(1);
#pragma unroll
      for (int mf = 0; mf < 4; ++mf)
#pragma unroll
        for (int nf = 0; nf < NHF; ++nf) {
          acc[mf][nf] = MFMA16(af[mf][0], bfr[nf][0], acc[mf][nf]);
          acc[mf][nf] = MFMA16(af[mf][1], bfr[nf][1], acc[mf][nf]);
        }
      __builtin_amdgcn_s_setprio(0);
      __builtin_amdgcn_s_barrier();

      // ---- phase 2: ds B(nh1); no staging ----
#pragma unroll
      for (int nf = NHF; nf < NREP; ++nf) {
        bfr[nf][0] = *(const bf16x8*)(Bc0 + nf * 2048);
        bfr[nf][1] = *(const bf16x8*)(Bc1 + nf * 2048);
      }
      __builtin_amdgcn_s_barrier();
      asm volatile("s_waitcnt lgkmcnt(0)" ::: "memory");
      __builtin_amdgcn_sched_barrier(0);
      __builtin_amdgcn_s_setprio(1);
#pragma unroll
      for (int mf = 0; mf < 4; ++mf)
#pragma unroll
        for (int nf = NHF; nf < NREP; ++nf) {
          acc[mf][nf] = MFMA16(af[mf][0], bfr[nf][0], acc[mf][nf]);
          acc[mf][nf] = MFMA16(af[mf][1], bfr[nf][1], acc[mf][nf]);
        }
      __builtin_amdgcn_s_setprio(0);
      __builtin_amdgcn_s_barrier();

      // ---- phase 3: ds A(mh1); stage B(kt+2) chunks 0,1 -> cur ----
#pragma unroll
      for (int mf = 0; mf < 4; ++mf) {
        af[mf][0] = *(const bf16x8*)(Ac0 + 8192 + mf * 2048);
        af[mf][1] = *(const bf16x8*)(Ac1 + 8192 + mf * 2048);
      }
      if (st2) {
        gl_lds16(sB + ko2, stB[cur]);
        gl_lds16(sB + (size_t)64 * K + ko2, stB[cur] + 8192);
      }
      __builtin_amdgcn_s_barrier();
      asm volatile("s_waitcnt lgkmcnt(0)" ::: "memory");
      __builtin_amdgcn_sched_barrier(0);
      __builtin_amdgcn_s_setprio(1);
#pragma unroll
      for (int mf = 0; mf < 4; ++mf)
#pragma unroll
        for (int nf = 0; nf < NHF; ++nf) {
          acc[4 + mf][nf] = MFMA16(af[mf][0], bfr[nf][0], acc[4 + mf][nf]);
          acc[4 + mf][nf] = MFMA16(af[mf][1], bfr[nf][1], acc[4 + mf][nf]);
        }
      __builtin_amdgcn_s_setprio(0);
      __builtin_amdgcn_s_barrier();

      // ---- phase 4: stage B(kt+2) chunks 2,3 (BN256) + A(kt+2)h0 -> cur ----
      if (st2) {
        if constexpr (BN_ == 256) {
          gl_lds16(sB + (size_t)128 * K + ko2, stB[cur] + 16384);
          gl_lds16(sB + (size_t)192 * K + ko2, stB[cur] + 24576);
        }
        gl_lds16(sAc0 + ko2, stA[cur]);
        gl_lds16(sAc1 + ko2, stA[cur] + 8192);
      }
      __builtin_amdgcn_s_setprio(1);
#pragma unroll
      for (int mf = 0; mf < 4; ++mf)
#pragma unroll
        for (int nf = NHF; nf < NREP; ++nf) {
          acc[4 + mf][nf] = MFMA16(af[mf][0], bfr[nf][0], acc[4 + mf][nf]);
          acc[4 + mf][nf] = MFMA16(af[mf][1], bfr[nf][1], acc[4 + mf][nf]);
        }
      __builtin_amdgcn_s_setprio(0);
      if (st2) {
        if constexpr (BN_ == 256) ASM_VMCNT(6); else ASM_VMCNT(4);
        __builtin_amdgcn_s_barrier();
      } else if (st1) {
        ASM_VMCNT(0);
        __builtin_amdgcn_s_barrier();
      }
    }
  }

  // ---- epilogue ----
  const int colb2 = bn * BN_ + wn * WNT;
  const int rowb = bm * 256 + wm * 128 + lg * 4;
  float bv[NREP];
#pragma unroll
  for (int nf = 0; nf < NREP; ++nf) bv[nf] = bias[colb2 + nf * 16 + lr];
#pragma unroll
  for (int mf = 0; mf < 8; ++mf) {
    if constexpr (MODE == 0 || MODE == 4) {
#pragma unroll
      for (int nf = 0; nf < NREP; ++nf) {
        const int col = colb2 + nf * 16 + lr;
#pragma unroll
        for (int r = 0; r < 4; ++r) {
          const int row = rowb + mf * 16 + r;
          const float v = acc[mf][nf][r] + bv[nf];
          const float gl = 0.5f * v * (1.0f + erff(v * 0.7071067811865475f));
          Hout[(size_t)row * N + col] = (bf16)gl;
        }
      }
    } else if constexpr (MODE == 1) {
      float gv[4];
#pragma unroll
      for (int r = 0; r < 4; ++r)
        gv[r] = gate[(size_t)(rowb + mf * 16 + r) * 8 + gidx];
#pragma unroll
      for (int nf = 0; nf < NREP; ++nf) {
        const int col = colb2 + nf * 16 + lr;
#pragma unroll
        for (int r = 0; r < 4; ++r) {
          const float v = acc[mf][nf][r] + bv[nf];
          Fout[(size_t)(rowb + mf * 16 + r) * N + col] += gv[r] * v;
        }
      }
    } else {  // MODE 3: scatter-add via token list
      const int* lp = lists + eid * 8192;
      int tok[4]; float gv[4];
#pragma unroll
      for (int r = 0; r < 4; ++r) {
        tok[r] = lp[rowb + mf * 16 + r];
        gv[r] = tok[r] >= 0 ? gate[(size_t)tok[r] * 8 + gidx] : 0.0f;
      }
#pragma unroll
      for (int nf = 0; nf < NREP; ++nf) {
        const int col = colb2 + nf * 16 + lr;
#pragma unroll
        for (int r = 0; r < 4; ++r) {
          if (tok[r] >= 0) {
            const float v = acc[mf][nf][r] + bv[nf];
            Fout[(size_t)tok[r] * N + col] += gv[r] * v;
          }
        }
      }
    }
  }
}

extern "C" void kernel_launch(void* const* d_in, const int* in_sizes, int n_in,
                              void* d_out, int out_size, void* d_ws,
                              size_t ws_size, hipStream_t stream) {
  const float* x = (const float*)d_in[0];
  const float* spec_b1 = (const float*)d_in[2];
  const float* spec_b2 = (const float*)d_in[4];
  const float* spec_rw = (const float*)d_in[5];
  const float* spec_rb = (const float*)d_in[6];
  const float* shr_b1 = (const float*)d_in[8];
  const float* shr_b2 = (const float*)d_in[10];
  const float* shr_rw = (const float*)d_in[11];
  const float* shr_rb = (const float*)d_in[12];
  const float* spec_w1 = (const float*)d_in[1];
  const float* spec_w2 = (const float*)d_in[3];
  const float* shr_w1 = (const float*)d_in[7];
  const float* shr_w2 = (const float*)d_in[9];
  float* out = (float*)d_out;

  char* ws = (char*)d_ws;
  const size_t OFF_W1 = 16777216;          // xb: 16 MB
  const size_t OFF_W2 = OFF_W1 + 50331648;
  const size_t OFF_H = OFF_W2 + 50331648;
  const size_t OFF_GATE = OFF_H + 67108864;
  const size_t OFF_AUX = OFF_GATE + 262144;
  const size_t OFF_CNT = OFF_AUX + 64;
  const size_t OFF_LIST = OFF_CNT + 64;
  bf16* xb = (bf16*)ws;
  bf16* w1t = (bf16*)(ws + OFF_W1);
  bf16* w2t = (bf16*)(ws + OFF_W2);
  bf16* hbuf = (bf16*)(ws + OFF_H);
  float* gate = (float*)(ws + OFF_GATE);
  float* auxg = (float*)(ws + OFF_AUX);
  int* cnt = (int*)(ws + OFF_CNT);
  int* lists = (int*)(ws + OFF_LIST);

  hipMemsetAsync(out, 0, (size_t)T_TOK * DDIM * 4, stream);
  hipMemsetAsync(auxg, 0, 32, stream);
  hipMemsetAsync(cnt, 0, 16, stream);
  hipMemsetAsync(lists, 0xFF, 4 * 8192 * 4, stream);  // -1 sentinel

  convert_x<<<(T_TOK * DDIM) / 2048, 256, 0, stream>>>(x, xb);
  transpose_convert<<<dim3(HDIM / 32, DDIM / 32, 4), 256, 0, stream>>>(
      spec_w1, w1t, DDIM, HDIM);
  transpose_convert<<<dim3(HDIM / 32, DDIM / 32, 2), 256, 0, stream>>>(
      shr_w1, w1t + (size_t)4 * DDIM * HDIM, DDIM, HDIM);
  transpose_convert<<<dim3(DDIM / 32, HDIM / 32, 4), 256, 0, stream>>>(
      spec_w2, w2t, HDIM, DDIM);
  transpose_convert<<<dim3(DDIM / 32, HDIM / 32, 2), 256, 0, stream>>>(
      shr_w2, w2t + (size_t)4 * DDIM * HDIM, HDIM, DDIM);
  router_kernel<<<T_TOK / 4, 256, 0, stream>>>(x, spec_rw, spec_rb, shr_rw,
                                               shr_rb, gate, auxg, cnt, lists);

  // ---- shared experts: dense over all tokens ----
  for (int es = 0; es < 2; ++es) {
    const bf16* w1e = w1t + (size_t)(4 + es) * DDIM * HDIM;
    const bf16* w2e = w2t + (size_t)(4 + es) * DDIM * HDIM;
    const float* b1e = shr_b1 + (size_t)es * HDIM;
    const float* b2e = shr_b2 + (size_t)es * DDIM;
    gemm4p<256, 0><<<512, 512, 0, stream>>>(
        xb, w1e, T_TOK, HDIM, DDIM, b1e, hbuf, nullptr, nullptr, 0,
        16, 8, 8, nullptr, nullptr, 0);
    gemm4p<128, 1><<<256, 512, 0, stream>>>(
        hbuf, w2e, T_TOK, DDIM, HDIM, b2e, nullptr, out, gate, 4 + es,
        8, 8, 4, nullptr, nullptr, 0);
  }

  // ---- specific experts: top-2 sparse (gather-on-stage, scatter-add) ----
  for (int e = 0; e < 4; ++e) {
    const bf16* w1e = w1t + (size_t)e * DDIM * HDIM;
    const bf16* w2e = w2t + (size_t)e * DDIM * HDIM;
    const float* b1e = spec_b1 + (size_t)e * HDIM;
    const float* b2e = spec_b2 + (size_t)e * DDIM;
    gemm4p<256, 4><<<512, 512, 0, stream>>>(
        xb, w1e, T_TOK, HDIM, DDIM, b1e, hbuf, nullptr, nullptr, 0,
        16, 0, 0, cnt, lists, e);
    gemm4p<128, 3><<<256, 512, 0, stream>>>(
        hbuf, w2e, T_TOK, DDIM, HDIM, b2e, nullptr, out, gate, e,
        8, 0, 0, cnt, lists, e);
  }
  aux_finalize<<<1, 1, 0, stream>>>(auxg, out + (size_t)T_TOK * DDIM);
}

// Round 7
// 1106.146 us; speedup vs baseline: 1.1823x; 1.1823x over previous
//
#include <hip/hip_runtime.h>
#include <hip/hip_bf16.h>

#define T_TOK 8192
#define DDIM 1024
#define HDIM 4096

typedef __bf16 bf16;
typedef bf16 bf16x8 __attribute__((ext_vector_type(8)));
typedef float f32x4 __attribute__((ext_vector_type(4)));

#define ASM_VMCNT(n) asm volatile("s_waitcnt vmcnt(" #n ")" ::: "memory")
#define MFMA16(a, b, c) __builtin_amdgcn_mfma_f32_16x16x32_bf16((a), (b), (c), 0, 0, 0)

__device__ __forceinline__ void gl_lds16(const void* g, void* l) {
  __builtin_amdgcn_global_load_lds(
      (const __attribute__((address_space(1))) unsigned int*)g,
      (__attribute__((address_space(3))) unsigned int*)l, 16, 0, 0);
}

// ---------------- x fp32 -> bf16 ----------------
__global__ __launch_bounds__(256) void convert_x(const float* __restrict__ x,
                                                 bf16* __restrict__ xb) {
  const size_t i = ((size_t)blockIdx.x * 256 + threadIdx.x) * 8;
  const float4 v0 = *(const float4*)(x + i);
  const float4 v1 = *(const float4*)(x + i + 4);
  bf16x8 o;
  o[0] = (bf16)v0.x; o[1] = (bf16)v0.y; o[2] = (bf16)v0.z; o[3] = (bf16)v0.w;
  o[4] = (bf16)v1.x; o[5] = (bf16)v1.y; o[6] = (bf16)v1.z; o[7] = (bf16)v1.w;
  *(bf16x8*)(xb + i) = o;
}

// ---------------- weight transpose + convert: src [R,C] f32 -> dst [C,R] bf16
__global__ __launch_bounds__(256) void transpose_convert(
    const float* __restrict__ src, bf16* __restrict__ dst, int R, int C) {
  __shared__ float tile[32][33];
  const size_t mat = (size_t)blockIdx.z * R * C;
  const int c0 = blockIdx.x * 32, r0 = blockIdx.y * 32;
  const int tx = threadIdx.x & 31, ty = threadIdx.x >> 5;  // 32 x 8
#pragma unroll
  for (int i = 0; i < 4; ++i)
    tile[ty + 8 * i][tx] =
        src[mat + (size_t)(r0 + ty + 8 * i) * C + c0 + tx];
  __syncthreads();
#pragma unroll
  for (int i = 0; i < 4; ++i)
    dst[mat + (size_t)(c0 + ty + 8 * i) * R + r0 + tx] =
        (bf16)tile[tx][ty + 8 * i];
}

// ---------------- router pass 1: probs/gates/top2 — NO atomics ----------------
__global__ __launch_bounds__(256) void router_probs(
    const float* __restrict__ x, const float* __restrict__ srw,
    const float* __restrict__ srb, const float* __restrict__ hrw,
    const float* __restrict__ hrb, float* __restrict__ gate,
    float4* __restrict__ probs4, int* __restrict__ top2) {
  const int lane = threadIdx.x & 63;
  const int w = threadIdx.x >> 6;
  const int t = blockIdx.x * 4 + w;

  const float* xr = x + (size_t)t * DDIM;
  float p0 = 0, p1 = 0, p2 = 0, p3 = 0, p4 = 0, p5 = 0;
#pragma unroll
  for (int c = 0; c < 4; ++c) {
    const int d = c * 256 + lane * 4;
    const float4 xv = *(const float4*)(xr + d);
    const float xa[4] = {xv.x, xv.y, xv.z, xv.w};
#pragma unroll
    for (int j = 0; j < 4; ++j) {
      const float xd = xa[j];
      const float4 r4 = *(const float4*)(srw + (size_t)(d + j) * 4);
      p0 += xd * r4.x; p1 += xd * r4.y; p2 += xd * r4.z; p3 += xd * r4.w;
      const float2 r2 = *(const float2*)(hrw + (size_t)(d + j) * 2);
      p4 += xd * r2.x; p5 += xd * r2.y;
    }
  }
#pragma unroll
  for (int off = 32; off >= 1; off >>= 1) {
    p0 += __shfl_xor(p0, off);
    p1 += __shfl_xor(p1, off);
    p2 += __shfl_xor(p2, off);
    p3 += __shfl_xor(p3, off);
    p4 += __shfl_xor(p4, off);
    p5 += __shfl_xor(p5, off);
  }
  if (lane == 0) {
    const float l0 = p0 + srb[0], l1 = p1 + srb[1];
    const float l2 = p2 + srb[2], l3 = p3 + srb[3];
    const float m = fmaxf(fmaxf(l0, l1), fmaxf(l2, l3));
    const float e0 = expf(l0 - m), e1 = expf(l1 - m);
    const float e2 = expf(l2 - m), e3 = expf(l3 - m);
    const float s = e0 + e1 + e2 + e3;
    float pr[4] = {e0 / s, e1 / s, e2 / s, e3 / s};
    int i1 = 0; float v1 = pr[0];
#pragma unroll
    for (int e = 1; e < 4; ++e) if (pr[e] > v1) { v1 = pr[e]; i1 = e; }
    int i2 = -1; float v2 = -1.0f;
#pragma unroll
    for (int e = 0; e < 4; ++e)
      if (e != i1 && pr[e] > v2) { v2 = pr[e]; i2 = e; }
    float g[4] = {0, 0, 0, 0};
    g[i1] = v1; g[i2] = v2;
    float* gr = gate + (size_t)t * 8;
    gr[0] = g[0]; gr[1] = g[1]; gr[2] = g[2]; gr[3] = g[3];
    const float h0 = p4 + hrb[0], h1 = p5 + hrb[1];
    const float mh = fmaxf(h0, h1);
    const float q0 = expf(h0 - mh), q1 = expf(h1 - mh);
    const float qs = q0 + q1;
    gr[4] = q0 / qs; gr[5] = q1 / qs; gr[6] = 0; gr[7] = 0;
    probs4[t] = make_float4(pr[0], pr[1], pr[2], pr[3]);
    top2[t] = i1 | (i2 << 8);
  }
}

// ---------------- router pass 2: single-block scan -> lists/cnt/aux ----------
__global__ __launch_bounds__(1024) void scan_build(
    const int* __restrict__ top2, const float4* __restrict__ probs4,
    int* __restrict__ cnt, int* __restrict__ lists, float* __restrict__ auxg) {
  __shared__ unsigned long long sc[1024];
  __shared__ float4 rp[512];
  const int tid = threadIdx.x;

  int ee[8];
  unsigned long long c = 0;
  float4 ps = make_float4(0.f, 0.f, 0.f, 0.f);
#pragma unroll
  for (int j = 0; j < 8; ++j) {
    const int t = tid * 8 + j;
    const int p = top2[t];
    ee[j] = p;
    const int a = p & 15, b = (p >> 8) & 15;
    c += (1ULL << (16 * a)) + (1ULL << (16 * b));
    const float4 pv = probs4[t];
    ps.x += pv.x; ps.y += pv.y; ps.z += pv.z; ps.w += pv.w;
  }
  sc[tid] = c;
  __syncthreads();
  for (int off = 1; off < 1024; off <<= 1) {
    const unsigned long long mine = sc[tid];
    const unsigned long long prev = (tid >= off) ? sc[tid - off] : 0ULL;
    __syncthreads();
    sc[tid] = mine + prev;
    __syncthreads();
  }
  const unsigned long long incl = sc[tid];
  const unsigned long long tot = sc[1023];
  const unsigned long long excl = incl - c;
  int q0 = (int)(excl & 0xffff), q1 = (int)((excl >> 16) & 0xffff);
  int q2 = (int)((excl >> 32) & 0xffff), q3 = (int)((excl >> 48) & 0xffff);
#pragma unroll
  for (int j = 0; j < 8; ++j) {
    const int t = tid * 8 + j;
    const int a = ee[j] & 15, b = (ee[j] >> 8) & 15;
    const int pa = (a == 0) ? q0 : (a == 1) ? q1 : (a == 2) ? q2 : q3;
    lists[a * 8192 + pa] = t;
    q0 += (a == 0); q1 += (a == 1); q2 += (a == 2); q3 += (a == 3);
    const int pb = (b == 0) ? q0 : (b == 1) ? q1 : (b == 2) ? q2 : q3;
    lists[b * 8192 + pb] = t;
    q0 += (b == 0); q1 += (b == 1); q2 += (b == 2); q3 += (b == 3);
  }
  if (tid == 1023) {
    const int c0 = (int)(tot & 0xffff), c1 = (int)((tot >> 16) & 0xffff);
    const int c2 = (int)((tot >> 32) & 0xffff), c3 = (int)((tot >> 48) & 0xffff);
    cnt[0] = c0; cnt[1] = c1; cnt[2] = c2; cnt[3] = c3;
    auxg[0] = (float)c0; auxg[1] = (float)c1;
    auxg[2] = (float)c2; auxg[3] = (float)c3;
  }
  // block reduce prob sums
  if (tid >= 512) rp[tid - 512] = ps;
  __syncthreads();
  if (tid < 512) {
    const float4 o = rp[tid];
    ps.x += o.x; ps.y += o.y; ps.z += o.z; ps.w += o.w;
  }
  for (int w = 256; w >= 1; w >>= 1) {
    __syncthreads();
    if (tid >= w && tid < 2 * w) rp[tid - w] = ps;
    __syncthreads();
    if (tid < w) {
      const float4 o = rp[tid];
      ps.x += o.x; ps.y += o.y; ps.z += o.z; ps.w += o.w;
    }
  }
  if (tid == 0) {
    auxg[4] = ps.x; auxg[5] = ps.y; auxg[6] = ps.z; auxg[7] = ps.w;
  }
}

__global__ void aux_finalize(const float* __restrict__ auxg,
                             float* __restrict__ outp) {
  float a = 0.0f;
#pragma unroll
  for (int e = 0; e < 4; ++e)
    a += (auxg[e] / (float)(T_TOK * 2)) * (auxg[4 + e] / (float)T_TOK);
  outp[0] = 4.0f * a;
}

// ---------------- 4-phase pipelined GEMM  C = A[M,K]*B[N,K]^T ----------------
// BM=256, BK=64, 8 waves (2Mx4N), 2-deep LDS dbuf, counted vmcnt (6/4),
// swizzle byte ^= ((row&7)<<4) in 128B rows (pre-swizzled global src + read).
// MODE 0: dense A, Hout = gelu(C+bias)                 (shared gemm1)
// MODE 4: gathered A via lists[eid], Hout = gelu       (spec gemm1)
// MODE 1: dense, Fout[row] += gate[row*8+gidx]*(C+b)   (shared gemm2 e1)
// MODE 2: dense, Fout[row]  = gate[row*8+gidx]*(C+b)   (shared gemm2 e0)
// MODE 3: scatter, Fout[tok] += gate[tok*8+gidx]*(C+b) (spec gemm2)
template <int BN_, int MODE>
__global__ __launch_bounds__(512, 2) void gemm4p(
    const bf16* __restrict__ A, const bf16* __restrict__ B, int M, int N,
    int K, const float* __restrict__ bias, bf16* __restrict__ Hout,
    float* __restrict__ Fout, const float* __restrict__ gate, int gidx,
    int NBn, int CH_M, int CH_N, const int* __restrict__ cnt,
    const int* __restrict__ lists, int eid) {
  constexpr int NREP = BN_ / 64;
  constexpr int NHF = NREP / 2;
  constexpr int WNT = BN_ / 4;
  constexpr int ABYTES = 256 * 64 * 2;
  constexpr int BBYTES = BN_ * 64 * 2;
  constexpr bool DYN = (MODE == 3 || MODE == 4);

  __shared__ __align__(1024) bf16 Alds[2 * 256 * 64];
  __shared__ __align__(1024) bf16 Blds[2 * BN_ * 64];

  const int tid = threadIdx.x;
  const int lane = tid & 63, wid = tid >> 6;
  const int wm = wid >> 2, wn = wid & 3;
  const int lr = lane & 15, lg = lane >> 4;

  int bm, bn;
  if constexpr (DYN) {
    // chunked XCD mapping over live grid: 8 XCDs = 4 m-chunks x 2 n-chunks
    const int nbm = ((cnt[eid] + 255) & ~255) >> 8;
    const int CHm = (nbm + 3) >> 2;
    constexpr int CHn = (BN_ == 256) ? 8 : 4;  // NBn/2
    const int need = 8 * CHm * CHn;
    if (blockIdx.x >= need) return;
    const int xc = blockIdx.x & 7;
    const int idx = blockIdx.x >> 3;
    const int cm = xc >> 1, cn = xc & 1;
    bm = cm * CHm + idx / CHn;
    bn = cn * CHn + idx % CHn;
    if (bm >= nbm) return;
  } else {
    const int xcd = blockIdx.x & 7;
    const int idx = blockIdx.x >> 3;
    const int ncn = NBn / CH_N;
    const int cm = xcd / ncn, cn = xcd % ncn;
    bm = cm * CH_M + idx / CH_N;
    bn = cn * CH_N + idx % CH_N;
  }

  const int NT = K >> 6;

  // ---- staging source (pre-swizzled global, linear LDS dest) ----
  const int L = tid * 16;
  const int rl = L >> 7;                         // row 0..63 within 8KB chunk
  const int colb = (L & 127) ^ ((rl & 7) << 4);  // swizzled col byte

  int ar0 = bm * 256 + rl, ar1 = ar0 + 64, ar2 = ar0 + 128, ar3 = ar0 + 192;
  if constexpr (MODE == 4) {
    const int* lp = lists + eid * 8192;
    int t;
    t = lp[ar0]; ar0 = t < 0 ? 0 : t;
    t = lp[ar1]; ar1 = t < 0 ? 0 : t;
    t = lp[ar2]; ar2 = t < 0 ? 0 : t;
    t = lp[ar3]; ar3 = t < 0 ? 0 : t;
  }
  const bf16* sAc0 = A + (size_t)ar0 * K + (colb >> 1);
  const bf16* sAc1 = A + (size_t)ar1 * K + (colb >> 1);
  const bf16* sAc2 = A + (size_t)ar2 * K + (colb >> 1);
  const bf16* sAc3 = A + (size_t)ar3 * K + (colb >> 1);
  const bf16* sB = B + (size_t)(bn * BN_ + rl) * K + (colb >> 1);

  char* const ldsA = (char*)Alds;
  char* const ldsB = (char*)Blds;
  const int wb = wid * 1024;
  char* const stA[2] = {ldsA + wb, ldsA + ABYTES + wb};
  char* const stB[2] = {ldsB + wb, ldsB + BBYTES + wb};

  const int ax0 = (lg * 16) ^ ((lr & 7) << 4);
  const int ax1 = ax0 ^ 64;
  const int aro = (wm * 128 + lr) * 128;
  const int bro = (wn * WNT + lr) * 128;
  const char* const Ak0[2] = {ldsA + aro + ax0, ldsA + ABYTES + aro + ax0};
  const char* const Ak1[2] = {ldsA + aro + ax1, ldsA + ABYTES + aro + ax1};
  const char* const Bk0[2] = {ldsB + bro + ax0, ldsB + BBYTES + bro + ax0};
  const char* const Bk1[2] = {ldsB + bro + ax1, ldsB + BBYTES + bro + ax1};

  f32x4 acc[8][NREP] = {};

  // ---- prologue: T0 full, then T1 {B h0, B h1, A h0} ----
  gl_lds16(sAc0, stA[0]);
  gl_lds16(sAc1, stA[0] + 8192);
  gl_lds16(sAc2, stA[0] + 16384);
  gl_lds16(sAc3, stA[0] + 24576);
  gl_lds16(sB, stB[0]);
  gl_lds16(sB + (size_t)64 * K, stB[0] + 8192);
  if constexpr (BN_ == 256) {
    gl_lds16(sB + (size_t)128 * K, stB[0] + 16384);
    gl_lds16(sB + (size_t)192 * K, stB[0] + 24576);
  }
  gl_lds16(sB + 64, stB[1]);
  gl_lds16(sB + (size_t)64 * K + 64, stB[1] + 8192);
  if constexpr (BN_ == 256) {
    gl_lds16(sB + (size_t)128 * K + 64, stB[1] + 16384);
    gl_lds16(sB + (size_t)192 * K + 64, stB[1] + 24576);
  }
  gl_lds16(sAc0 + 64, stA[1]);
  gl_lds16(sAc1 + 64, stA[1] + 8192);
  if constexpr (BN_ == 256) ASM_VMCNT(6); else ASM_VMCNT(4);
  __builtin_amdgcn_s_barrier();

  for (int kt0 = 0; kt0 < NT; kt0 += 2) {
#pragma unroll
    for (int par = 0; par < 2; ++par) {
      const int kt = kt0 + par;
      const int cur = par, oth = par ^ 1;
      const bool st1 = (kt + 1) < NT, st2 = (kt + 2) < NT;
      const size_t ko1 = (size_t)(kt + 1) << 6, ko2 = (size_t)(kt + 2) << 6;
      const char* Ac0 = Ak0[cur]; const char* Ac1 = Ak1[cur];
      const char* Bc0 = Bk0[cur]; const char* Bc1 = Bk1[cur];

      bf16x8 af[4][2], bfr[NREP][2];

      // ---- phase 1: ds A(mh0)+B(nh0); stage A(kt+1)h1 -> oth ----
#pragma unroll
      for (int mf = 0; mf < 4; ++mf) {
        af[mf][0] = *(const bf16x8*)(Ac0 + mf * 2048);
        af[mf][1] = *(const bf16x8*)(Ac1 + mf * 2048);
      }
#pragma unroll
      for (int nf = 0; nf < NHF; ++nf) {
        bfr[nf][0] = *(const bf16x8*)(Bc0 + nf * 2048);
        bfr[nf][1] = *(const bf16x8*)(Bc1 + nf * 2048);
      }
      if (st1) {
        gl_lds16(sAc2 + ko1, stA[oth] + 16384);
        gl_lds16(sAc3 + ko1, stA[oth] + 24576);
      }
      __builtin_amdgcn_s_barrier();
      asm volatile("s_waitcnt lgkmcnt(0)" ::: "memory");
      __builtin_amdgcn_sched_barrier(0);
      __builtin_amdgcn_s_setprio(1);
#pragma unroll
      for (int mf = 0; mf < 4; ++mf)
#pragma unroll
        for (int nf = 0; nf < NHF; ++nf) {
          acc[mf][nf] = MFMA16(af[mf][0], bfr[nf][0], acc[mf][nf]);
          acc[mf][nf] = MFMA16(af[mf][1], bfr[nf][1], acc[mf][nf]);
        }
      __builtin_amdgcn_s_setprio(0);
      __builtin_amdgcn_s_barrier();

      // ---- phase 2: ds B(nh1); no staging ----
#pragma unroll
      for (int nf = NHF; nf < NREP; ++nf) {
        bfr[nf][0] = *(const bf16x8*)(Bc0 + nf * 2048);
        bfr[nf][1] = *(const bf16x8*)(Bc1 + nf * 2048);
      }
      __builtin_amdgcn_s_barrier();
      asm volatile("s_waitcnt lgkmcnt(0)" ::: "memory");
      __builtin_amdgcn_sched_barrier(0);
      __builtin_amdgcn_s_setprio(1);
#pragma unroll
      for (int mf = 0; mf < 4; ++mf)
#pragma unroll
        for (int nf = NHF; nf < NREP; ++nf) {
          acc[mf][nf] = MFMA16(af[mf][0], bfr[nf][0], acc[mf][nf]);
          acc[mf][nf] = MFMA16(af[mf][1], bfr[nf][1], acc[mf][nf]);
        }
      __builtin_amdgcn_s_setprio(0);
      __builtin_amdgcn_s_barrier();

      // ---- phase 3: ds A(mh1); stage B(kt+2) chunks 0,1 -> cur ----
#pragma unroll
      for (int mf = 0; mf < 4; ++mf) {
        af[mf][0] = *(const bf16x8*)(Ac0 + 8192 + mf * 2048);
        af[mf][1] = *(const bf16x8*)(Ac1 + 8192 + mf * 2048);
      }
      if (st2) {
        gl_lds16(sB + ko2, stB[cur]);
        gl_lds16(sB + (size_t)64 * K + ko2, stB[cur] + 8192);
      }
      __builtin_amdgcn_s_barrier();
      asm volatile("s_waitcnt lgkmcnt(0)" ::: "memory");
      __builtin_amdgcn_sched_barrier(0);
      __builtin_amdgcn_s_setprio(1);
#pragma unroll
      for (int mf = 0; mf < 4; ++mf)
#pragma unroll
        for (int nf = 0; nf < NHF; ++nf) {
          acc[4 + mf][nf] = MFMA16(af[mf][0], bfr[nf][0], acc[4 + mf][nf]);
          acc[4 + mf][nf] = MFMA16(af[mf][1], bfr[nf][1], acc[4 + mf][nf]);
        }
      __builtin_amdgcn_s_setprio(0);
      __builtin_amdgcn_s_barrier();

      // ---- phase 4: stage B(kt+2) chunks 2,3 (BN256) + A(kt+2)h0 -> cur ----
      if (st2) {
        if constexpr (BN_ == 256) {
          gl_lds16(sB + (size_t)128 * K + ko2, stB[cur] + 16384);
          gl_lds16(sB + (size_t)192 * K + ko2, stB[cur] + 24576);
        }
        gl_lds16(sAc0 + ko2, stA[cur]);
        gl_lds16(sAc1 + ko2, stA[cur] + 8192);
      }
      __builtin_amdgcn_s_setprio(1);
#pragma unroll
      for (int mf = 0; mf < 4; ++mf)
#pragma unroll
        for (int nf = NHF; nf < NREP; ++nf) {
          acc[4 + mf][nf] = MFMA16(af[mf][0], bfr[nf][0], acc[4 + mf][nf]);
          acc[4 + mf][nf] = MFMA16(af[mf][1], bfr[nf][1], acc[4 + mf][nf]);
        }
      __builtin_amdgcn_s_setprio(0);
      if (st2) {
        if constexpr (BN_ == 256) ASM_VMCNT(6); else ASM_VMCNT(4);
        __builtin_amdgcn_s_barrier();
      } else if (st1) {
        ASM_VMCNT(0);
        __builtin_amdgcn_s_barrier();
      }
    }
  }

  // ---- epilogue ----
  const int colb2 = bn * BN_ + wn * WNT;
  const int rowb = bm * 256 + wm * 128 + lg * 4;
  float bv[NREP];
#pragma unroll
  for (int nf = 0; nf < NREP; ++nf) bv[nf] = bias[colb2 + nf * 16 + lr];
#pragma unroll
  for (int mf = 0; mf < 8; ++mf) {
    if constexpr (MODE == 0 || MODE == 4) {
#pragma unroll
      for (int nf = 0; nf < NREP; ++nf) {
        const int col = colb2 + nf * 16 + lr;
#pragma unroll
        for (int r = 0; r < 4; ++r) {
          const int row = rowb + mf * 16 + r;
          const float v = acc[mf][nf][r] + bv[nf];
          const float gl = 0.5f * v * (1.0f + erff(v * 0.7071067811865475f));
          Hout[(size_t)row * N + col] = (bf16)gl;
        }
      }
    } else if constexpr (MODE == 1 || MODE == 2) {
      float gv[4];
#pragma unroll
      for (int r = 0; r < 4; ++r)
        gv[r] = gate[(size_t)(rowb + mf * 16 + r) * 8 + gidx];
#pragma unroll
      for (int nf = 0; nf < NREP; ++nf) {
        const int col = colb2 + nf * 16 + lr;
#pragma unroll
        for (int r = 0; r < 4; ++r) {
          const float v = acc[mf][nf][r] + bv[nf];
          const size_t oi = (size_t)(rowb + mf * 16 + r) * N + col;
          if constexpr (MODE == 1)
            Fout[oi] += gv[r] * v;
          else
            Fout[oi] = gv[r] * v;
        }
      }
    } else {  // MODE 3: scatter-add via token list
      const int* lp = lists + eid * 8192;
      int tok[4]; float gv[4];
#pragma unroll
      for (int r = 0; r < 4; ++r) {
        tok[r] = lp[rowb + mf * 16 + r];
        gv[r] = tok[r] >= 0 ? gate[(size_t)tok[r] * 8 + gidx] : 0.0f;
      }
#pragma unroll
      for (int nf = 0; nf < NREP; ++nf) {
        const int col = colb2 + nf * 16 + lr;
#pragma unroll
        for (int r = 0; r < 4; ++r) {
          if (tok[r] >= 0) {
            const float v = acc[mf][nf][r] + bv[nf];
            Fout[(size_t)tok[r] * N + col] += gv[r] * v;
          }
        }
      }
    }
  }
}

extern "C" void kernel_launch(void* const* d_in, const int* in_sizes, int n_in,
                              void* d_out, int out_size, void* d_ws,
                              size_t ws_size, hipStream_t stream) {
  const float* x = (const float*)d_in[0];
  const float* spec_w1 = (const float*)d_in[1];
  const float* spec_b1 = (const float*)d_in[2];
  const float* spec_w2 = (const float*)d_in[3];
  const float* spec_b2 = (const float*)d_in[4];
  const float* spec_rw = (const float*)d_in[5];
  const float* spec_rb = (const float*)d_in[6];
  const float* shr_w1 = (const float*)d_in[7];
  const float* shr_b1 = (const float*)d_in[8];
  const float* shr_w2 = (const float*)d_in[9];
  const float* shr_b2 = (const float*)d_in[10];
  const float* shr_rw = (const float*)d_in[11];
  const float* shr_rb = (const float*)d_in[12];
  float* out = (float*)d_out;

  char* ws = (char*)d_ws;
  const size_t OFF_W1 = 16777216;            // xb: 16 MB
  const size_t OFF_W2 = OFF_W1 + 50331648;   // w1t: 48 MB
  const size_t OFF_H = OFF_W2 + 50331648;    // w2t: 48 MB
  const size_t OFF_GATE = OFF_H + 67108864;  // hbuf: 64 MB
  const size_t OFF_AUX = OFF_GATE + 262144;
  const size_t OFF_CNT = OFF_AUX + 64;
  const size_t OFF_LIST = OFF_CNT + 64;
  const size_t OFF_T2 = OFF_LIST + 131072;
  const size_t OFF_P4 = OFF_T2 + 32768;
  bf16* xb = (bf16*)ws;
  bf16* w1t = (bf16*)(ws + OFF_W1);
  bf16* w2t = (bf16*)(ws + OFF_W2);
  bf16* hbuf = (bf16*)(ws + OFF_H);
  float* gate = (float*)(ws + OFF_GATE);
  float* auxg = (float*)(ws + OFF_AUX);
  int* cnt = (int*)(ws + OFF_CNT);
  int* lists = (int*)(ws + OFF_LIST);
  int* top2 = (int*)(ws + OFF_T2);
  float4* probs4 = (float4*)(ws + OFF_P4);

  hipMemsetAsync(lists, 0xFF, 4 * 8192 * 4, stream);  // -1 sentinel

  convert_x<<<(T_TOK * DDIM) / 2048, 256, 0, stream>>>(x, xb);
  transpose_convert<<<dim3(HDIM / 32, DDIM / 32, 4), 256, 0, stream>>>(
      spec_w1, w1t, DDIM, HDIM);
  transpose_convert<<<dim3(HDIM / 32, DDIM / 32, 2), 256, 0, stream>>>(
      shr_w1, w1t + (size_t)4 * DDIM * HDIM, DDIM, HDIM);
  transpose_convert<<<dim3(DDIM / 32, HDIM / 32, 4), 256, 0, stream>>>(
      spec_w2, w2t, HDIM, DDIM);
  transpose_convert<<<dim3(DDIM / 32, HDIM / 32, 2), 256, 0, stream>>>(
      shr_w2, w2t + (size_t)4 * DDIM * HDIM, HDIM, DDIM);

  router_probs<<<T_TOK / 4, 256, 0, stream>>>(x, spec_rw, spec_rb, shr_rw,
                                              shr_rb, gate, probs4, top2);
  scan_build<<<1, 1024, 0, stream>>>(top2, probs4, cnt, lists, auxg);

  // ---- shared experts: dense over all tokens (e0 writes, e1 accumulates) ----
  for (int es = 0; es < 2; ++es) {
    const bf16* w1e = w1t + (size_t)(4 + es) * DDIM * HDIM;
    const bf16* w2e = w2t + (size_t)(4 + es) * DDIM * HDIM;
    const float* b1e = shr_b1 + (size_t)es * HDIM;
    const float* b2e = shr_b2 + (size_t)es * DDIM;
    gemm4p<256, 0><<<512, 512, 0, stream>>>(
        xb, w1e, T_TOK, HDIM, DDIM, b1e, hbuf, nullptr, nullptr, 0,
        16, 8, 8, nullptr, nullptr, 0);
    if (es == 0)
      gemm4p<128, 2><<<256, 512, 0, stream>>>(
          hbuf, w2e, T_TOK, DDIM, HDIM, b2e, nullptr, out, gate, 4,
          8, 8, 4, nullptr, nullptr, 0);
    else
      gemm4p<128, 1><<<256, 512, 0, stream>>>(
          hbuf, w2e, T_TOK, DDIM, HDIM, b2e, nullptr, out, gate, 5,
          8, 8, 4, nullptr, nullptr, 0);
  }

  // ---- specific experts: top-2 sparse (gather-on-stage, scatter-add) ----
  for (int e = 0; e < 4; ++e) {
    const bf16* w1e = w1t + (size_t)e * DDIM * HDIM;
    const bf16* w2e = w2t + (size_t)e * DDIM * HDIM;
    const float* b1e = spec_b1 + (size_t)e * HDIM;
    const float* b2e = spec_b2 + (size_t)e * DDIM;
    gemm4p<256, 4><<<512, 512, 0, stream>>>(
        xb, w1e, T_TOK, HDIM, DDIM, b1e, hbuf, nullptr, nullptr, 0,
        16, 0, 0, cnt, lists, e);
    gemm4p<128, 3><<<256, 512, 0, stream>>>(
        hbuf, w2e, T_TOK, DDIM, HDIM, b2e, nullptr, out, gate, e,
        8, 0, 0, cnt, lists, e);
  }
  aux_finalize<<<1, 1, 0, stream>>>(auxg, out + (size_t)T_TOK * DDIM);
}

// Round 8
// 1059.216 us; speedup vs baseline: 1.2347x; 1.0443x over previous
//
#include <hip/hip_runtime.h>
#include <hip/hip_bf16.h>

#define T_TOK 8192
#define DDIM 1024
#define HDIM 4096

typedef __bf16 bf16;
typedef bf16 bf16x8 __attribute__((ext_vector_type(8)));
typedef float f32x4 __attribute__((ext_vector_type(4)));

#define ASM_VMCNT(n) asm volatile("s_waitcnt vmcnt(" #n ")" ::: "memory")
#define MFMA16(a, b, c) __builtin_amdgcn_mfma_f32_16x16x32_bf16((a), (b), (c), 0, 0, 0)

__device__ __forceinline__ void gl_lds16(const void* g, void* l) {
  __builtin_amdgcn_global_load_lds(
      (const __attribute__((address_space(1))) unsigned int*)g,
      (__attribute__((address_space(3))) unsigned int*)l, 16, 0, 0);
}

// ---------------- x fp32 -> bf16 ----------------
__global__ __launch_bounds__(256) void convert_x(const float* __restrict__ x,
                                                 bf16* __restrict__ xb) {
  const size_t i = ((size_t)blockIdx.x * 256 + threadIdx.x) * 8;
  const float4 v0 = *(const float4*)(x + i);
  const float4 v1 = *(const float4*)(x + i + 4);
  bf16x8 o;
  o[0] = (bf16)v0.x; o[1] = (bf16)v0.y; o[2] = (bf16)v0.z; o[3] = (bf16)v0.w;
  o[4] = (bf16)v1.x; o[5] = (bf16)v1.y; o[6] = (bf16)v1.z; o[7] = (bf16)v1.w;
  *(bf16x8*)(xb + i) = o;
}

// ---------------- weight transpose + convert: src [R,C] f32 -> dst [C,R] bf16
__global__ __launch_bounds__(256) void transpose_convert(
    const float* __restrict__ src, bf16* __restrict__ dst, int R, int C) {
  __shared__ float tile[32][33];
  const size_t mat = (size_t)blockIdx.z * R * C;
  const int c0 = blockIdx.x * 32, r0 = blockIdx.y * 32;
  const int tx = threadIdx.x & 31, ty = threadIdx.x >> 5;  // 32 x 8
#pragma unroll
  for (int i = 0; i < 4; ++i)
    tile[ty + 8 * i][tx] =
        src[mat + (size_t)(r0 + ty + 8 * i) * C + c0 + tx];
  __syncthreads();
#pragma unroll
  for (int i = 0; i < 4; ++i)
    dst[mat + (size_t)(c0 + ty + 8 * i) * R + r0 + tx] =
        (bf16)tile[tx][ty + 8 * i];
}

// ---------------- router pass 1: probs/gates/top2 — NO atomics ----------------
__global__ __launch_bounds__(256) void router_probs(
    const float* __restrict__ x, const float* __restrict__ srw,
    const float* __restrict__ srb, const float* __restrict__ hrw,
    const float* __restrict__ hrb, float* __restrict__ gate,
    float4* __restrict__ probs4, int* __restrict__ top2) {
  const int lane = threadIdx.x & 63;
  const int w = threadIdx.x >> 6;
  const int t = blockIdx.x * 4 + w;

  const float* xr = x + (size_t)t * DDIM;
  float p0 = 0, p1 = 0, p2 = 0, p3 = 0, p4 = 0, p5 = 0;
#pragma unroll
  for (int c = 0; c < 4; ++c) {
    const int d = c * 256 + lane * 4;
    const float4 xv = *(const float4*)(xr + d);
    const float xa[4] = {xv.x, xv.y, xv.z, xv.w};
#pragma unroll
    for (int j = 0; j < 4; ++j) {
      const float xd = xa[j];
      const float4 r4 = *(const float4*)(srw + (size_t)(d + j) * 4);
      p0 += xd * r4.x; p1 += xd * r4.y; p2 += xd * r4.z; p3 += xd * r4.w;
      const float2 r2 = *(const float2*)(hrw + (size_t)(d + j) * 2);
      p4 += xd * r2.x; p5 += xd * r2.y;
    }
  }
#pragma unroll
  for (int off = 32; off >= 1; off >>= 1) {
    p0 += __shfl_xor(p0, off);
    p1 += __shfl_xor(p1, off);
    p2 += __shfl_xor(p2, off);
    p3 += __shfl_xor(p3, off);
    p4 += __shfl_xor(p4, off);
    p5 += __shfl_xor(p5, off);
  }
  if (lane == 0) {
    const float l0 = p0 + srb[0], l1 = p1 + srb[1];
    const float l2 = p2 + srb[2], l3 = p3 + srb[3];
    const float m = fmaxf(fmaxf(l0, l1), fmaxf(l2, l3));
    const float e0 = expf(l0 - m), e1 = expf(l1 - m);
    const float e2 = expf(l2 - m), e3 = expf(l3 - m);
    const float s = e0 + e1 + e2 + e3;
    float pr[4] = {e0 / s, e1 / s, e2 / s, e3 / s};
    int i1 = 0; float v1 = pr[0];
#pragma unroll
    for (int e = 1; e < 4; ++e) if (pr[e] > v1) { v1 = pr[e]; i1 = e; }
    int i2 = -1; float v2 = -1.0f;
#pragma unroll
    for (int e = 0; e < 4; ++e)
      if (e != i1 && pr[e] > v2) { v2 = pr[e]; i2 = e; }
    float g[4] = {0, 0, 0, 0};
    g[i1] = v1; g[i2] = v2;
    float* gr = gate + (size_t)t * 8;
    gr[0] = g[0]; gr[1] = g[1]; gr[2] = g[2]; gr[3] = g[3];
    const float h0 = p4 + hrb[0], h1 = p5 + hrb[1];
    const float mh = fmaxf(h0, h1);
    const float q0 = expf(h0 - mh), q1 = expf(h1 - mh);
    const float qs = q0 + q1;
    gr[4] = q0 / qs; gr[5] = q1 / qs; gr[6] = 0; gr[7] = 0;
    probs4[t] = make_float4(pr[0], pr[1], pr[2], pr[3]);
    top2[t] = i1 | (i2 << 8);
  }
}

// ---------------- router pass 2: single-block scan -> lists/cnt/aux ----------
__global__ __launch_bounds__(1024) void scan_build(
    const int* __restrict__ top2, const float4* __restrict__ probs4,
    int* __restrict__ cnt, int* __restrict__ lists, float* __restrict__ auxg) {
  __shared__ unsigned long long sc[1024];
  __shared__ float4 rp[512];
  const int tid = threadIdx.x;

  int ee[8];
  unsigned long long c = 0;
  float4 ps = make_float4(0.f, 0.f, 0.f, 0.f);
#pragma unroll
  for (int j = 0; j < 8; ++j) {
    const int t = tid * 8 + j;
    const int p = top2[t];
    ee[j] = p;
    const int a = p & 15, b = (p >> 8) & 15;
    c += (1ULL << (16 * a)) + (1ULL << (16 * b));
    const float4 pv = probs4[t];
    ps.x += pv.x; ps.y += pv.y; ps.z += pv.z; ps.w += pv.w;
  }
  sc[tid] = c;
  __syncthreads();
  for (int off = 1; off < 1024; off <<= 1) {
    const unsigned long long mine = sc[tid];
    const unsigned long long prev = (tid >= off) ? sc[tid - off] : 0ULL;
    __syncthreads();
    sc[tid] = mine + prev;
    __syncthreads();
  }
  const unsigned long long incl = sc[tid];
  const unsigned long long tot = sc[1023];
  const unsigned long long excl = incl - c;
  int q0 = (int)(excl & 0xffff), q1 = (int)((excl >> 16) & 0xffff);
  int q2 = (int)((excl >> 32) & 0xffff), q3 = (int)((excl >> 48) & 0xffff);
#pragma unroll
  for (int j = 0; j < 8; ++j) {
    const int t = tid * 8 + j;
    const int a = ee[j] & 15, b = (ee[j] >> 8) & 15;
    const int pa = (a == 0) ? q0 : (a == 1) ? q1 : (a == 2) ? q2 : q3;
    lists[a * 8192 + pa] = t;
    q0 += (a == 0); q1 += (a == 1); q2 += (a == 2); q3 += (a == 3);
    const int pb = (b == 0) ? q0 : (b == 1) ? q1 : (b == 2) ? q2 : q3;
    lists[b * 8192 + pb] = t;
    q0 += (b == 0); q1 += (b == 1); q2 += (b == 2); q3 += (b == 3);
  }
  if (tid == 1023) {
    const int c0 = (int)(tot & 0xffff), c1 = (int)((tot >> 16) & 0xffff);
    const int c2 = (int)((tot >> 32) & 0xffff), c3 = (int)((tot >> 48) & 0xffff);
    cnt[0] = c0; cnt[1] = c1; cnt[2] = c2; cnt[3] = c3;
    auxg[0] = (float)c0; auxg[1] = (float)c1;
    auxg[2] = (float)c2; auxg[3] = (float)c3;
  }
  // block reduce prob sums
  if (tid >= 512) rp[tid - 512] = ps;
  __syncthreads();
  if (tid < 512) {
    const float4 o = rp[tid];
    ps.x += o.x; ps.y += o.y; ps.z += o.z; ps.w += o.w;
  }
  for (int w = 256; w >= 1; w >>= 1) {
    __syncthreads();
    if (tid >= w && tid < 2 * w) rp[tid - w] = ps;
    __syncthreads();
    if (tid < w) {
      const float4 o = rp[tid];
      ps.x += o.x; ps.y += o.y; ps.z += o.z; ps.w += o.w;
    }
  }
  if (tid == 0) {
    auxg[4] = ps.x; auxg[5] = ps.y; auxg[6] = ps.z; auxg[7] = ps.w;
  }
}

__global__ void aux_finalize(const float* __restrict__ auxg,
                             float* __restrict__ outp) {
  float a = 0.0f;
#pragma unroll
  for (int e = 0; e < 4; ++e)
    a += (auxg[e] / (float)(T_TOK * 2)) * (auxg[4 + e] / (float)T_TOK);
  outp[0] = 4.0f * a;
}

// ---------------- gemmv: m97-family GEMM1  H = gelu(A*B^T + b) ----------------
// 128x128 tile, BK=32, 4 waves (2Mx2N), 16 KB LDS single-buffer, 2 barriers/tile,
// 3 blocks/CU (launch_bounds 256,3) -> inter-block latency hiding.
// Swizzle: byte ^= (((row>>1)&3)<<4) within 64B rows, both sides.
// MODE 0: dense A. MODE 4: A rows gathered via lists[eid] (spec experts).
template <int MODE>
__global__ __launch_bounds__(256, 3) void gemmv(
    const bf16* __restrict__ A, const bf16* __restrict__ B, int N, int K,
    const float* __restrict__ bias, bf16* __restrict__ Hout, int NBn,
    int CH_M, int CH_N, const int* __restrict__ cnt,
    const int* __restrict__ lists, int eid) {
  __shared__ __align__(1024) bf16 As[128 * 32];
  __shared__ __align__(1024) bf16 Bs[128 * 32];

  const int tid = threadIdx.x;
  const int lane = tid & 63, wid = tid >> 6;
  const int wm = wid >> 1, wn = wid & 1;
  const int lr = lane & 15, lg = lane >> 4;

  int bm, bn;
  if constexpr (MODE == 4) {
    const int nbm = ((cnt[eid] + 127) & ~127) >> 7;
    const int CHm = (nbm + 3) >> 2;          // 4 m-chunks x 2 n-chunks
    const int need = 8 * CHm * CH_N;
    if (blockIdx.x >= need) return;
    const int xc = blockIdx.x & 7;
    const int idx = blockIdx.x >> 3;
    bm = (xc >> 1) * CHm + idx / CH_N;
    bn = (xc & 1) * CH_N + idx % CH_N;
    if (bm >= nbm) return;
  } else {
    const int xcd = blockIdx.x & 7;
    const int idx = blockIdx.x >> 3;
    const int ncn = NBn / CH_N;
    bm = (xcd / ncn) * CH_M + idx / CH_N;
    bn = (xcd % ncn) * CH_N + idx % CH_N;
  }

  // ---- staging source (pre-swizzled global, linear LDS dest) ----
  const int rl = tid >> 2;                                   // row 0..63
  const int c = ((tid & 3) * 16) ^ (((rl >> 1) & 3) << 4);   // swizzled col byte
  int ar0 = bm * 128 + rl, ar1 = ar0 + 64;
  if constexpr (MODE == 4) {
    const int* lp = lists + eid * 8192;
    int t = lp[ar0]; ar0 = t < 0 ? 0 : t;
    t = lp[ar1]; ar1 = t < 0 ? 0 : t;
  }
  const bf16* sA0 = A + (size_t)ar0 * K + (c >> 1);
  const bf16* sA1 = A + (size_t)ar1 * K + (c >> 1);
  const bf16* sB0 = B + (size_t)(bn * 128 + rl) * K + (c >> 1);
  const bf16* sB1 = B + (size_t)(bn * 128 + 64 + rl) * K + (c >> 1);
  char* const dA0 = (char*)As + wid * 1024;
  char* const dA1 = (char*)As + 4096 + wid * 1024;
  char* const dB0 = (char*)Bs + wid * 1024;
  char* const dB1 = (char*)Bs + 4096 + wid * 1024;

  // ---- swizzled ds_read bases ----
  const int rkey = ((lr >> 1) & 3) << 4;
  const char* Ard = (const char*)As + (wm * 64 + lr) * 64 + ((lg * 16) ^ rkey);
  const char* Brd = (const char*)Bs + (wn * 64 + lr) * 64 + ((lg * 16) ^ rkey);

  f32x4 acc[4][4] = {};
  const int NT = K >> 5;
  for (int kt = 0; kt < NT; ++kt) {
    const int ko = kt << 5;
    gl_lds16(sA0 + ko, dA0);
    gl_lds16(sA1 + ko, dA1);
    gl_lds16(sB0 + ko, dB0);
    gl_lds16(sB1 + ko, dB1);
    __syncthreads();
    bf16x8 af[4], bfr[4];
#pragma unroll
    for (int mf = 0; mf < 4; ++mf) af[mf] = *(const bf16x8*)(Ard + mf * 1024);
#pragma unroll
    for (int nf = 0; nf < 4; ++nf) bfr[nf] = *(const bf16x8*)(Brd + nf * 1024);
    __builtin_amdgcn_s_setprio(1);
#pragma unroll
    for (int mf = 0; mf < 4; ++mf)
#pragma unroll
      for (int nf = 0; nf < 4; ++nf)
        acc[mf][nf] = MFMA16(af[mf], bfr[nf], acc[mf][nf]);
    __builtin_amdgcn_s_setprio(0);
    __syncthreads();
  }

  // ---- epilogue: gelu -> Hout ----
  const int colb = bn * 128 + wn * 64;
  const int rowb = bm * 128 + wm * 64 + lg * 4;
  float bv[4];
#pragma unroll
  for (int nf = 0; nf < 4; ++nf) bv[nf] = bias[colb + nf * 16 + lr];
#pragma unroll
  for (int mf = 0; mf < 4; ++mf)
#pragma unroll
    for (int nf = 0; nf < 4; ++nf) {
      const int col = colb + nf * 16 + lr;
#pragma unroll
      for (int r = 0; r < 4; ++r) {
        const int row = rowb + mf * 16 + r;
        const float v = acc[mf][nf][r] + bv[nf];
        const float gl = 0.5f * v * (1.0f + erff(v * 0.7071067811865475f));
        Hout[(size_t)row * N + col] = (bf16)gl;
      }
    }
}

// ---------------- 4-phase pipelined GEMM2 (unchanged, measured 37%) ----------
// MODE 1: dense, Fout[row] += gate[row*8+gidx]*(C+b)
// MODE 2: dense, Fout[row]  = gate[row*8+gidx]*(C+b)
// MODE 3: scatter, Fout[tok] += gate[tok*8+gidx]*(C+b)
template <int BN_, int MODE>
__global__ __launch_bounds__(512, 2) void gemm4p(
    const bf16* __restrict__ A, const bf16* __restrict__ B, int M, int N,
    int K, const float* __restrict__ bias, bf16* __restrict__ Hout,
    float* __restrict__ Fout, const float* __restrict__ gate, int gidx,
    int NBn, int CH_M, int CH_N, const int* __restrict__ cnt,
    const int* __restrict__ lists, int eid) {
  constexpr int NREP = BN_ / 64;
  constexpr int NHF = NREP / 2;
  constexpr int WNT = BN_ / 4;
  constexpr int ABYTES = 256 * 64 * 2;
  constexpr int BBYTES = BN_ * 64 * 2;
  constexpr bool DYN = (MODE == 3);

  __shared__ __align__(1024) bf16 Alds[2 * 256 * 64];
  __shared__ __align__(1024) bf16 Blds[2 * BN_ * 64];

  const int tid = threadIdx.x;
  const int lane = tid & 63, wid = tid >> 6;
  const int wm = wid >> 2, wn = wid & 3;
  const int lr = lane & 15, lg = lane >> 4;

  int bm, bn;
  if constexpr (DYN) {
    const int nbm = ((cnt[eid] + 255) & ~255) >> 8;
    const int CHm = (nbm + 3) >> 2;
    constexpr int CHn = (BN_ == 256) ? 8 : 4;
    const int need = 8 * CHm * CHn;
    if (blockIdx.x >= need) return;
    const int xc = blockIdx.x & 7;
    const int idx = blockIdx.x >> 3;
    bm = (xc >> 1) * CHm + idx / CHn;
    bn = (xc & 1) * CHn + idx % CHn;
    if (bm >= nbm) return;
  } else {
    const int xcd = blockIdx.x & 7;
    const int idx = blockIdx.x >> 3;
    const int ncn = NBn / CH_N;
    bm = (xcd / ncn) * CH_M + idx / CH_N;
    bn = (xcd % ncn) * CH_N + idx % CH_N;
  }

  const int NT = K >> 6;

  const int L = tid * 16;
  const int rl = L >> 7;
  const int colb = (L & 127) ^ ((rl & 7) << 4);

  const int ar0 = bm * 256 + rl;
  const bf16* sAc0 = A + (size_t)ar0 * K + (colb >> 1);
  const bf16* sAc1 = A + (size_t)(ar0 + 64) * K + (colb >> 1);
  const bf16* sAc2 = A + (size_t)(ar0 + 128) * K + (colb >> 1);
  const bf16* sAc3 = A + (size_t)(ar0 + 192) * K + (colb >> 1);
  const bf16* sB = B + (size_t)(bn * BN_ + rl) * K + (colb >> 1);

  char* const ldsA = (char*)Alds;
  char* const ldsB = (char*)Blds;
  const int wb = wid * 1024;
  char* const stA[2] = {ldsA + wb, ldsA + ABYTES + wb};
  char* const stB[2] = {ldsB + wb, ldsB + BBYTES + wb};

  const int ax0 = (lg * 16) ^ ((lr & 7) << 4);
  const int ax1 = ax0 ^ 64;
  const int aro = (wm * 128 + lr) * 128;
  const int bro = (wn * WNT + lr) * 128;
  const char* const Ak0[2] = {ldsA + aro + ax0, ldsA + ABYTES + aro + ax0};
  const char* const Ak1[2] = {ldsA + aro + ax1, ldsA + ABYTES + aro + ax1};
  const char* const Bk0[2] = {ldsB + bro + ax0, ldsB + BBYTES + bro + ax0};
  const char* const Bk1[2] = {ldsB + bro + ax1, ldsB + BBYTES + bro + ax1};

  f32x4 acc[8][NREP] = {};

  gl_lds16(sAc0, stA[0]);
  gl_lds16(sAc1, stA[0] + 8192);
  gl_lds16(sAc2, stA[0] + 16384);
  gl_lds16(sAc3, stA[0] + 24576);
  gl_lds16(sB, stB[0]);
  gl_lds16(sB + (size_t)64 * K, stB[0] + 8192);
  if constexpr (BN_ == 256) {
    gl_lds16(sB + (size_t)128 * K, stB[0] + 16384);
    gl_lds16(sB + (size_t)192 * K, stB[0] + 24576);
  }
  gl_lds16(sB + 64, stB[1]);
  gl_lds16(sB + (size_t)64 * K + 64, stB[1] + 8192);
  if constexpr (BN_ == 256) {
    gl_lds16(sB + (size_t)128 * K + 64, stB[1] + 16384);
    gl_lds16(sB + (size_t)192 * K + 64, stB[1] + 24576);
  }
  gl_lds16(sAc0 + 64, stA[1]);
  gl_lds16(sAc1 + 64, stA[1] + 8192);
  if constexpr (BN_ == 256) ASM_VMCNT(6); else ASM_VMCNT(4);
  __builtin_amdgcn_s_barrier();

  for (int kt0 = 0; kt0 < NT; kt0 += 2) {
#pragma unroll
    for (int par = 0; par < 2; ++par) {
      const int kt = kt0 + par;
      const int cur = par, oth = par ^ 1;
      const bool st1 = (kt + 1) < NT, st2 = (kt + 2) < NT;
      const size_t ko1 = (size_t)(kt + 1) << 6, ko2 = (size_t)(kt + 2) << 6;
      const char* Ac0 = Ak0[cur]; const char* Ac1 = Ak1[cur];
      const char* Bc0 = Bk0[cur]; const char* Bc1 = Bk1[cur];

      bf16x8 af[4][2], bfr[NREP][2];

#pragma unroll
      for (int mf = 0; mf < 4; ++mf) {
        af[mf][0] = *(const bf16x8*)(Ac0 + mf * 2048);
        af[mf][1] = *(const bf16x8*)(Ac1 + mf * 2048);
      }
#pragma unroll
      for (int nf = 0; nf < NHF; ++nf) {
        bfr[nf][0] = *(const bf16x8*)(Bc0 + nf * 2048);
        bfr[nf][1] = *(const bf16x8*)(Bc1 + nf * 2048);
      }
      if (st1) {
        gl_lds16(sAc2 + ko1, stA[oth] + 16384);
        gl_lds16(sAc3 + ko1, stA[oth] + 24576);
      }
      __builtin_amdgcn_s_barrier();
      asm volatile("s_waitcnt lgkmcnt(0)" ::: "memory");
      __builtin_amdgcn_sched_barrier(0);
      __builtin_amdgcn_s_setprio(1);
#pragma unroll
      for (int mf = 0; mf < 4; ++mf)
#pragma unroll
        for (int nf = 0; nf < NHF; ++nf) {
          acc[mf][nf] = MFMA16(af[mf][0], bfr[nf][0], acc[mf][nf]);
          acc[mf][nf] = MFMA16(af[mf][1], bfr[nf][1], acc[mf][nf]);
        }
      __builtin_amdgcn_s_setprio(0);
      __builtin_amdgcn_s_barrier();

#pragma unroll
      for (int nf = NHF; nf < NREP; ++nf) {
        bfr[nf][0] = *(const bf16x8*)(Bc0 + nf * 2048);
        bfr[nf][1] = *(const bf16x8*)(Bc1 + nf * 2048);
      }
      __builtin_amdgcn_s_barrier();
      asm volatile("s_waitcnt lgkmcnt(0)" ::: "memory");
      __builtin_amdgcn_sched_barrier(0);
      __builtin_amdgcn_s_setprio(1);
#pragma unroll
      for (int mf = 0; mf < 4; ++mf)
#pragma unroll
        for (int nf = NHF; nf < NREP; ++nf) {
          acc[mf][nf] = MFMA16(af[mf][0], bfr[nf][0], acc[mf][nf]);
          acc[mf][nf] = MFMA16(af[mf][1], bfr[nf][1], acc[mf][nf]);
        }
      __builtin_amdgcn_s_setprio(0);
      __builtin_amdgcn_s_barrier();

#pragma unroll
      for (int mf = 0; mf < 4; ++mf) {
        af[mf][0] = *(const bf16x8*)(Ac0 + 8192 + mf * 2048);
        af[mf][1] = *(const bf16x8*)(Ac1 + 8192 + mf * 2048);
      }
      if (st2) {
        gl_lds16(sB + ko2, stB[cur]);
        gl_lds16(sB + (size_t)64 * K + ko2, stB[cur] + 8192);
      }
      __builtin_amdgcn_s_barrier();
      asm volatile("s_waitcnt lgkmcnt(0)" ::: "memory");
      __builtin_amdgcn_sched_barrier(0);
      __builtin_amdgcn_s_setprio(1);
#pragma unroll
      for (int mf = 0; mf < 4; ++mf)
#pragma unroll
        for (int nf = 0; nf < NHF; ++nf) {
          acc[4 + mf][nf] = MFMA16(af[mf][0], bfr[nf][0], acc[4 + mf][nf]);
          acc[4 + mf][nf] = MFMA16(af[mf][1], bfr[nf][1], acc[4 + mf][nf]);
        }
      __builtin_amdgcn_s_setprio(0);
      __builtin_amdgcn_s_barrier();

      if (st2) {
        if constexpr (BN_ == 256) {
          gl_lds16(sB + (size_t)128 * K + ko2, stB[cur] + 16384);
          gl_lds16(sB + (size_t)192 * K + ko2, stB[cur] + 24576);
        }
        gl_lds16(sAc0 + ko2, stA[cur]);
        gl_lds16(sAc1 + ko2, stA[cur] + 8192);
      }
      __builtin_amdgcn_s_setprio(1);
#pragma unroll
      for (int mf = 0; mf < 4; ++mf)
#pragma unroll
        for (int nf = NHF; nf < NREP; ++nf) {
          acc[4 + mf][nf] = MFMA16(af[mf][0], bfr[nf][0], acc[4 + mf][nf]);
          acc[4 + mf][nf] = MFMA16(af[mf][1], bfr[nf][1], acc[4 + mf][nf]);
        }
      __builtin_amdgcn_s_setprio(0);
      if (st2) {
        if constexpr (BN_ == 256) ASM_VMCNT(6); else ASM_VMCNT(4);
        __builtin_amdgcn_s_barrier();
      } else if (st1) {
        ASM_VMCNT(0);
        __builtin_amdgcn_s_barrier();
      }
    }
  }

  const int colb2 = bn * BN_ + wn * WNT;
  const int rowb = bm * 256 + wm * 128 + lg * 4;
  float bv[NREP];
#pragma unroll
  for (int nf = 0; nf < NREP; ++nf) bv[nf] = bias[colb2 + nf * 16 + lr];
#pragma unroll
  for (int mf = 0; mf < 8; ++mf) {
    if constexpr (MODE == 1 || MODE == 2) {
      float gv[4];
#pragma unroll
      for (int r = 0; r < 4; ++r)
        gv[r] = gate[(size_t)(rowb + mf * 16 + r) * 8 + gidx];
#pragma unroll
      for (int nf = 0; nf < NREP; ++nf) {
        const int col = colb2 + nf * 16 + lr;
#pragma unroll
        for (int r = 0; r < 4; ++r) {
          const float v = acc[mf][nf][r] + bv[nf];
          const size_t oi = (size_t)(rowb + mf * 16 + r) * N + col;
          if constexpr (MODE == 1)
            Fout[oi] += gv[r] * v;
          else
            Fout[oi] = gv[r] * v;
        }
      }
    } else {  // MODE 3: scatter-add via token list
      const int* lp = lists + eid * 8192;
      int tok[4]; float gv[4];
#pragma unroll
      for (int r = 0; r < 4; ++r) {
        tok[r] = lp[rowb + mf * 16 + r];
        gv[r] = tok[r] >= 0 ? gate[(size_t)tok[r] * 8 + gidx] : 0.0f;
      }
#pragma unroll
      for (int nf = 0; nf < NREP; ++nf) {
        const int col = colb2 + nf * 16 + lr;
#pragma unroll
        for (int r = 0; r < 4; ++r) {
          if (tok[r] >= 0) {
            const float v = acc[mf][nf][r] + bv[nf];
            Fout[(size_t)tok[r] * N + col] += gv[r] * v;
          }
        }
      }
    }
  }
}

extern "C" void kernel_launch(void* const* d_in, const int* in_sizes, int n_in,
                              void* d_out, int out_size, void* d_ws,
                              size_t ws_size, hipStream_t stream) {
  const float* x = (const float*)d_in[0];
  const float* spec_w1 = (const float*)d_in[1];
  const float* spec_b1 = (const float*)d_in[2];
  const float* spec_w2 = (const float*)d_in[3];
  const float* spec_b2 = (const float*)d_in[4];
  const float* spec_rw = (const float*)d_in[5];
  const float* spec_rb = (const float*)d_in[6];
  const float* shr_w1 = (const float*)d_in[7];
  const float* shr_b1 = (const float*)d_in[8];
  const float* shr_w2 = (const float*)d_in[9];
  const float* shr_b2 = (const float*)d_in[10];
  const float* shr_rw = (const float*)d_in[11];
  const float* shr_rb = (const float*)d_in[12];
  float* out = (float*)d_out;

  char* ws = (char*)d_ws;
  const size_t OFF_W1 = 16777216;            // xb: 16 MB
  const size_t OFF_W2 = OFF_W1 + 50331648;   // w1t: 48 MB
  const size_t OFF_H = OFF_W2 + 50331648;    // w2t: 48 MB
  const size_t OFF_GATE = OFF_H + 67108864;  // hbuf: 64 MB
  const size_t OFF_AUX = OFF_GATE + 262144;
  const size_t OFF_CNT = OFF_AUX + 64;
  const size_t OFF_LIST = OFF_CNT + 64;
  const size_t OFF_T2 = OFF_LIST + 131072;
  const size_t OFF_P4 = OFF_T2 + 32768;
  bf16* xb = (bf16*)ws;
  bf16* w1t = (bf16*)(ws + OFF_W1);
  bf16* w2t = (bf16*)(ws + OFF_W2);
  bf16* hbuf = (bf16*)(ws + OFF_H);
  float* gate = (float*)(ws + OFF_GATE);
  float* auxg = (float*)(ws + OFF_AUX);
  int* cnt = (int*)(ws + OFF_CNT);
  int* lists = (int*)(ws + OFF_LIST);
  int* top2 = (int*)(ws + OFF_T2);
  float4* probs4 = (float4*)(ws + OFF_P4);

  hipMemsetAsync(lists, 0xFF, 4 * 8192 * 4, stream);  // -1 sentinel

  convert_x<<<(T_TOK * DDIM) / 2048, 256, 0, stream>>>(x, xb);
  transpose_convert<<<dim3(HDIM / 32, DDIM / 32, 4), 256, 0, stream>>>(
      spec_w1, w1t, DDIM, HDIM);
  transpose_convert<<<dim3(HDIM / 32, DDIM / 32, 2), 256, 0, stream>>>(
      shr_w1, w1t + (size_t)4 * DDIM * HDIM, DDIM, HDIM);
  transpose_convert<<<dim3(DDIM / 32, HDIM / 32, 4), 256, 0, stream>>>(
      spec_w2, w2t, HDIM, DDIM);
  transpose_convert<<<dim3(DDIM / 32, HDIM / 32, 2), 256, 0, stream>>>(
      shr_w2, w2t + (size_t)4 * DDIM * HDIM, HDIM, DDIM);

  router_probs<<<T_TOK / 4, 256, 0, stream>>>(x, spec_rw, spec_rb, shr_rw,
                                              shr_rb, gate, probs4, top2);
  scan_build<<<1, 1024, 0, stream>>>(top2, probs4, cnt, lists, auxg);

  // ---- shared experts: dense over all tokens (e0 writes, e1 accumulates) ----
  for (int es = 0; es < 2; ++es) {
    const bf16* w1e = w1t + (size_t)(4 + es) * DDIM * HDIM;
    const bf16* w2e = w2t + (size_t)(4 + es) * DDIM * HDIM;
    const float* b1e = shr_b1 + (size_t)es * HDIM;
    const float* b2e = shr_b2 + (size_t)es * DDIM;
    // gemm1: 128^2 tiles, grid 64x32 = 2048, chunks 16x16 (4m x 2n XCDs)
    gemmv<0><<<2048, 256, 0, stream>>>(xb, w1e, HDIM, DDIM, b1e, hbuf,
                                       32, 16, 16, nullptr, nullptr, 0);
    if (es == 0)
      gemm4p<128, 2><<<256, 512, 0, stream>>>(
          hbuf, w2e, T_TOK, DDIM, HDIM, b2e, nullptr, out, gate, 4,
          8, 8, 4, nullptr, nullptr, 0);
    else
      gemm4p<128, 1><<<256, 512, 0, stream>>>(
          hbuf, w2e, T_TOK, DDIM, HDIM, b2e, nullptr, out, gate, 5,
          8, 8, 4, nullptr, nullptr, 0);
  }

  // ---- specific experts: top-2 sparse (gather-on-stage, scatter-add) ----
  for (int e = 0; e < 4; ++e) {
    const bf16* w1e = w1t + (size_t)e * DDIM * HDIM;
    const bf16* w2e = w2t + (size_t)e * DDIM * HDIM;
    const float* b1e = spec_b1 + (size_t)e * HDIM;
    const float* b2e = spec_b2 + (size_t)e * DDIM;
    gemmv<4><<<2048, 256, 0, stream>>>(xb, w1e, HDIM, DDIM, b1e, hbuf,
                                       32, 0, 16, cnt, lists, e);
    gemm4p<128, 3><<<256, 512, 0, stream>>>(
        hbuf, w2e, T_TOK, DDIM, HDIM, b2e, nullptr, out, gate, e,
        8, 0, 0, cnt, lists, e);
  }
  aux_finalize<<<1, 1, 0, stream>>>(auxg, out + (size_t)T_TOK * DDIM);
}

// Round 9
// 1044.898 us; speedup vs baseline: 1.2516x; 1.0137x over previous
//
#include <hip/hip_runtime.h>
#include <hip/hip_bf16.h>

#define T_TOK 8192
#define DDIM 1024
#define HDIM 4096

typedef __bf16 bf16;
typedef bf16 bf16x8 __attribute__((ext_vector_type(8)));
typedef float f32x4 __attribute__((ext_vector_type(4)));

#define ASM_VMCNT(n) asm volatile("s_waitcnt vmcnt(" #n ")" ::: "memory")
#define MFMA16(a, b, c) __builtin_amdgcn_mfma_f32_16x16x32_bf16((a), (b), (c), 0, 0, 0)

__device__ __forceinline__ void gl_lds16(const void* g, void* l) {
  __builtin_amdgcn_global_load_lds(
      (const __attribute__((address_space(1))) unsigned int*)g,
      (__attribute__((address_space(3))) unsigned int*)l, 16, 0, 0);
}

// Fast exact-grade GELU: erf via Abramowitz-Stegun 7.1.26 (|err|<=1.5e-7,
// far below bf16 rounding). ~16 VALU ops vs ~40+ for libm erff.
__device__ __forceinline__ float gelu_f(float v) {
  const float x = v * 0.7071067811865475f;
  const float ax = fabsf(x);
  const float t = 1.0f / fmaf(0.3275911f, ax, 1.0f);
  float p = fmaf(1.061405429f, t, -1.453152027f);
  p = fmaf(p, t, 1.421413741f);
  p = fmaf(p, t, -0.284496736f);
  p = fmaf(p, t, 0.254829592f);
  p = p * t;
  const float e = __expf(-ax * ax);
  const float er = fmaf(-p, e, 1.0f);  // erf(|x|)
  const float erfx = (x >= 0.0f) ? er : -er;
  return 0.5f * v * (1.0f + erfx);
}

// ---------------- x fp32 -> bf16 ----------------
__global__ __launch_bounds__(256) void convert_x(const float* __restrict__ x,
                                                 bf16* __restrict__ xb) {
  const size_t i = ((size_t)blockIdx.x * 256 + threadIdx.x) * 8;
  const float4 v0 = *(const float4*)(x + i);
  const float4 v1 = *(const float4*)(x + i + 4);
  bf16x8 o;
  o[0] = (bf16)v0.x; o[1] = (bf16)v0.y; o[2] = (bf16)v0.z; o[3] = (bf16)v0.w;
  o[4] = (bf16)v1.x; o[5] = (bf16)v1.y; o[6] = (bf16)v1.z; o[7] = (bf16)v1.w;
  *(bf16x8*)(xb + i) = o;
}

// ---------------- weight transpose + convert: src [R,C] f32 -> dst [C,R] bf16
__global__ __launch_bounds__(256) void transpose_convert(
    const float* __restrict__ src, bf16* __restrict__ dst, int R, int C) {
  __shared__ float tile[32][33];
  const size_t mat = (size_t)blockIdx.z * R * C;
  const int c0 = blockIdx.x * 32, r0 = blockIdx.y * 32;
  const int tx = threadIdx.x & 31, ty = threadIdx.x >> 5;  // 32 x 8
#pragma unroll
  for (int i = 0; i < 4; ++i)
    tile[ty + 8 * i][tx] =
        src[mat + (size_t)(r0 + ty + 8 * i) * C + c0 + tx];
  __syncthreads();
#pragma unroll
  for (int i = 0; i < 4; ++i)
    dst[mat + (size_t)(c0 + ty + 8 * i) * R + r0 + tx] =
        (bf16)tile[tx][ty + 8 * i];
}

// ---------------- router pass 1: probs/gates/top2 — NO atomics ----------------
__global__ __launch_bounds__(256) void router_probs(
    const float* __restrict__ x, const float* __restrict__ srw,
    const float* __restrict__ srb, const float* __restrict__ hrw,
    const float* __restrict__ hrb, float* __restrict__ gate,
    float4* __restrict__ probs4, int* __restrict__ top2) {
  const int lane = threadIdx.x & 63;
  const int w = threadIdx.x >> 6;
  const int t = blockIdx.x * 4 + w;

  const float* xr = x + (size_t)t * DDIM;
  float p0 = 0, p1 = 0, p2 = 0, p3 = 0, p4 = 0, p5 = 0;
#pragma unroll
  for (int c = 0; c < 4; ++c) {
    const int d = c * 256 + lane * 4;
    const float4 xv = *(const float4*)(xr + d);
    const float xa[4] = {xv.x, xv.y, xv.z, xv.w};
#pragma unroll
    for (int j = 0; j < 4; ++j) {
      const float xd = xa[j];
      const float4 r4 = *(const float4*)(srw + (size_t)(d + j) * 4);
      p0 += xd * r4.x; p1 += xd * r4.y; p2 += xd * r4.z; p3 += xd * r4.w;
      const float2 r2 = *(const float2*)(hrw + (size_t)(d + j) * 2);
      p4 += xd * r2.x; p5 += xd * r2.y;
    }
  }
#pragma unroll
  for (int off = 32; off >= 1; off >>= 1) {
    p0 += __shfl_xor(p0, off);
    p1 += __shfl_xor(p1, off);
    p2 += __shfl_xor(p2, off);
    p3 += __shfl_xor(p3, off);
    p4 += __shfl_xor(p4, off);
    p5 += __shfl_xor(p5, off);
  }
  if (lane == 0) {
    const float l0 = p0 + srb[0], l1 = p1 + srb[1];
    const float l2 = p2 + srb[2], l3 = p3 + srb[3];
    const float m = fmaxf(fmaxf(l0, l1), fmaxf(l2, l3));
    const float e0 = expf(l0 - m), e1 = expf(l1 - m);
    const float e2 = expf(l2 - m), e3 = expf(l3 - m);
    const float s = e0 + e1 + e2 + e3;
    float pr[4] = {e0 / s, e1 / s, e2 / s, e3 / s};
    int i1 = 0; float v1 = pr[0];
#pragma unroll
    for (int e = 1; e < 4; ++e) if (pr[e] > v1) { v1 = pr[e]; i1 = e; }
    int i2 = -1; float v2 = -1.0f;
#pragma unroll
    for (int e = 0; e < 4; ++e)
      if (e != i1 && pr[e] > v2) { v2 = pr[e]; i2 = e; }
    float g[4] = {0, 0, 0, 0};
    g[i1] = v1; g[i2] = v2;
    float* gr = gate + (size_t)t * 8;
    gr[0] = g[0]; gr[1] = g[1]; gr[2] = g[2]; gr[3] = g[3];
    const float h0 = p4 + hrb[0], h1 = p5 + hrb[1];
    const float mh = fmaxf(h0, h1);
    const float q0 = expf(h0 - mh), q1 = expf(h1 - mh);
    const float qs = q0 + q1;
    gr[4] = q0 / qs; gr[5] = q1 / qs; gr[6] = 0; gr[7] = 0;
    probs4[t] = make_float4(pr[0], pr[1], pr[2], pr[3]);
    top2[t] = i1 | (i2 << 8);
  }
}

// ---------------- router pass 2: single-block scan -> lists/cnt/aux ----------
__global__ __launch_bounds__(1024) void scan_build(
    const int* __restrict__ top2, const float4* __restrict__ probs4,
    int* __restrict__ cnt, int* __restrict__ lists, float* __restrict__ auxg) {
  __shared__ unsigned long long sc[1024];
  __shared__ float4 rp[512];
  const int tid = threadIdx.x;

  int ee[8];
  unsigned long long c = 0;
  float4 ps = make_float4(0.f, 0.f, 0.f, 0.f);
#pragma unroll
  for (int j = 0; j < 8; ++j) {
    const int t = tid * 8 + j;
    const int p = top2[t];
    ee[j] = p;
    const int a = p & 15, b = (p >> 8) & 15;
    c += (1ULL << (16 * a)) + (1ULL << (16 * b));
    const float4 pv = probs4[t];
    ps.x += pv.x; ps.y += pv.y; ps.z += pv.z; ps.w += pv.w;
  }
  sc[tid] = c;
  __syncthreads();
  for (int off = 1; off < 1024; off <<= 1) {
    const unsigned long long mine = sc[tid];
    const unsigned long long prev = (tid >= off) ? sc[tid - off] : 0ULL;
    __syncthreads();
    sc[tid] = mine + prev;
    __syncthreads();
  }
  const unsigned long long incl = sc[tid];
  const unsigned long long tot = sc[1023];
  const unsigned long long excl = incl - c;
  int q0 = (int)(excl & 0xffff), q1 = (int)((excl >> 16) & 0xffff);
  int q2 = (int)((excl >> 32) & 0xffff), q3 = (int)((excl >> 48) & 0xffff);
#pragma unroll
  for (int j = 0; j < 8; ++j) {
    const int t = tid * 8 + j;
    const int a = ee[j] & 15, b = (ee[j] >> 8) & 15;
    const int pa = (a == 0) ? q0 : (a == 1) ? q1 : (a == 2) ? q2 : q3;
    lists[a * 8192 + pa] = t;
    q0 += (a == 0); q1 += (a == 1); q2 += (a == 2); q3 += (a == 3);
    const int pb = (b == 0) ? q0 : (b == 1) ? q1 : (b == 2) ? q2 : q3;
    lists[b * 8192 + pb] = t;
    q0 += (b == 0); q1 += (b == 1); q2 += (b == 2); q3 += (b == 3);
  }
  if (tid == 1023) {
    const int c0 = (int)(tot & 0xffff), c1 = (int)((tot >> 16) & 0xffff);
    const int c2 = (int)((tot >> 32) & 0xffff), c3 = (int)((tot >> 48) & 0xffff);
    cnt[0] = c0; cnt[1] = c1; cnt[2] = c2; cnt[3] = c3;
    auxg[0] = (float)c0; auxg[1] = (float)c1;
    auxg[2] = (float)c2; auxg[3] = (float)c3;
  }
  if (tid >= 512) rp[tid - 512] = ps;
  __syncthreads();
  if (tid < 512) {
    const float4 o = rp[tid];
    ps.x += o.x; ps.y += o.y; ps.z += o.z; ps.w += o.w;
  }
  for (int w = 256; w >= 1; w >>= 1) {
    __syncthreads();
    if (tid >= w && tid < 2 * w) rp[tid - w] = ps;
    __syncthreads();
    if (tid < w) {
      const float4 o = rp[tid];
      ps.x += o.x; ps.y += o.y; ps.z += o.z; ps.w += o.w;
    }
  }
  if (tid == 0) {
    auxg[4] = ps.x; auxg[5] = ps.y; auxg[6] = ps.z; auxg[7] = ps.w;
  }
}

__global__ void aux_finalize(const float* __restrict__ auxg,
                             float* __restrict__ outp) {
  float a = 0.0f;
#pragma unroll
  for (int e = 0; e < 4; ++e)
    a += (auxg[e] / (float)(T_TOK * 2)) * (auxg[4 + e] / (float)T_TOK);
  outp[0] = 4.0f * a;
}

// ---------------- gemmv: ring-3 GEMM1  H = gelu(A*B^T + b) ----------------
// 128x128 tile, BK=32, 4 waves, 48 KB LDS (3-slot ring), 3 blocks/CU.
// Counted vmcnt: while computing tile t, tiles t+1,t+2 in flight (8 loads);
// end-of-iter stages t+3 then waits vmcnt(8) (tail 4 -> 0) — never a full
// drain mid-loop. Raw s_barrier (NOT __syncthreads: that drains vmcnt).
// Swizzle: byte ^= (((row>>1)&3)<<4) within 64B rows, both sides.
// MODE 0: dense A. MODE 4: A rows gathered via lists[eid] (spec experts).
template <int MODE>
__global__ __launch_bounds__(256, 3) void gemmv(
    const bf16* __restrict__ A, const bf16* __restrict__ B, int N, int K,
    const float* __restrict__ bias, bf16* __restrict__ Hout, int NBn,
    int CH_M, int CH_N, const int* __restrict__ cnt,
    const int* __restrict__ lists, int eid) {
  __shared__ __align__(1024) bf16 As[3 * 128 * 32];  // 24 KB
  __shared__ __align__(1024) bf16 Bs[3 * 128 * 32];  // 24 KB

  const int tid = threadIdx.x;
  const int lane = tid & 63, wid = tid >> 6;
  const int wm = wid >> 1, wn = wid & 1;
  const int lr = lane & 15, lg = lane >> 4;

  int bm, bn;
  if constexpr (MODE == 4) {
    const int nbm = ((cnt[eid] + 127) & ~127) >> 7;
    const int CHm = (nbm + 3) >> 2;          // 4 m-chunks x 2 n-chunks
    const int need = 8 * CHm * CH_N;
    if (blockIdx.x >= need) return;
    const int xc = blockIdx.x & 7;
    const int idx = blockIdx.x >> 3;
    bm = (xc >> 1) * CHm + idx / CH_N;
    bn = (xc & 1) * CH_N + idx % CH_N;
    if (bm >= nbm) return;
  } else {
    const int xcd = blockIdx.x & 7;
    const int idx = blockIdx.x >> 3;
    const int ncn = NBn / CH_N;
    bm = (xcd / ncn) * CH_M + idx / CH_N;
    bn = (xcd % ncn) * CH_N + idx % CH_N;
  }

  // ---- staging source (pre-swizzled global, linear LDS dest) ----
  const int rl = tid >> 2;                                   // row 0..63
  const int c = ((tid & 3) * 16) ^ (((rl >> 1) & 3) << 4);   // swizzled col byte
  int ar0 = bm * 128 + rl, ar1 = ar0 + 64;
  if constexpr (MODE == 4) {
    const int* lp = lists + eid * 8192;
    int t = lp[ar0]; ar0 = t < 0 ? 0 : t;
    t = lp[ar1]; ar1 = t < 0 ? 0 : t;
  }
  const bf16* sA0 = A + (size_t)ar0 * K + (c >> 1);
  const bf16* sA1 = A + (size_t)ar1 * K + (c >> 1);
  const bf16* sB0 = B + (size_t)(bn * 128 + rl) * K + (c >> 1);
  const bf16* sB1 = B + (size_t)(bn * 128 + 64 + rl) * K + (c >> 1);
  char* const dA0 = (char*)As + wid * 1024;       // + slot*8192
  char* const dA1 = (char*)As + 4096 + wid * 1024;
  char* const dB0 = (char*)Bs + wid * 1024;
  char* const dB1 = (char*)Bs + 4096 + wid * 1024;

  // ---- swizzled ds_read bases ----
  const int rkey = ((lr >> 1) & 3) << 4;
  const char* Ard = (const char*)As + (wm * 64 + lr) * 64 + ((lg * 16) ^ rkey);
  const char* Brd = (const char*)Bs + (wn * 64 + lr) * 64 + ((lg * 16) ^ rkey);

  f32x4 acc[4][4] = {};
  const int NT = K >> 5;

  // ---- prologue: stage tiles 0,1,2 into slots 0,1,2 ----
#define GV_STAGE(KO, SLOT)                    \
  gl_lds16(sA0 + (KO), dA0 + (SLOT)*8192);    \
  gl_lds16(sA1 + (KO), dA1 + (SLOT)*8192);    \
  gl_lds16(sB0 + (KO), dB0 + (SLOT)*8192);    \
  gl_lds16(sB1 + (KO), dB1 + (SLOT)*8192);
  GV_STAGE(0, 0)
  GV_STAGE(32, 1)
  GV_STAGE(64, 2)
  ASM_VMCNT(8);
  __builtin_amdgcn_s_barrier();

#define GV_ITER(KT, SLOT)                                                  \
  {                                                                        \
    bf16x8 af[4], bfr[4];                                                  \
    _Pragma("unroll") for (int mf = 0; mf < 4; ++mf)                       \
        af[mf] = *(const bf16x8*)(Ard + (SLOT)*8192 + mf * 1024);          \
    _Pragma("unroll") for (int nf = 0; nf < 4; ++nf)                       \
        bfr[nf] = *(const bf16x8*)(Brd + (SLOT)*8192 + nf * 1024);         \
    asm volatile("s_waitcnt lgkmcnt(0)" ::: "memory");                     \
    __builtin_amdgcn_s_setprio(1);                                         \
    _Pragma("unroll") for (int mf = 0; mf < 4; ++mf)                       \
        _Pragma("unroll") for (int nf = 0; nf < 4; ++nf)                   \
            acc[mf][nf] = MFMA16(af[mf], bfr[nf], acc[mf][nf]);            \
    __builtin_amdgcn_s_setprio(0);                                         \
    __builtin_amdgcn_s_barrier();                                          \
    if ((KT) + 3 < NT) {                                                   \
      const int ko_ = ((KT) + 3) << 5;                                     \
      GV_STAGE(ko_, SLOT)                                                  \
      ASM_VMCNT(8);                                                        \
    } else if ((KT) + 2 < NT) {                                            \
      ASM_VMCNT(4);                                                        \
    } else if ((KT) + 1 < NT) {                                            \
      ASM_VMCNT(0);                                                        \
    }                                                                      \
    __builtin_amdgcn_s_barrier();                                          \
  }

  for (int kt0 = 0; kt0 < NT; kt0 += 3) {
    GV_ITER(kt0, 0)
    if (kt0 + 1 < NT) GV_ITER(kt0 + 1, 1)
    if (kt0 + 2 < NT) GV_ITER(kt0 + 2, 2)
  }

  // ---- epilogue: fast gelu -> Hout ----
  const int colb = bn * 128 + wn * 64;
  const int rowb = bm * 128 + wm * 64 + lg * 4;
  float bv[4];
#pragma unroll
  for (int nf = 0; nf < 4; ++nf) bv[nf] = bias[colb + nf * 16 + lr];
#pragma unroll
  for (int mf = 0; mf < 4; ++mf)
#pragma unroll
    for (int nf = 0; nf < 4; ++nf) {
      const int col = colb + nf * 16 + lr;
#pragma unroll
      for (int r = 0; r < 4; ++r) {
        const int row = rowb + mf * 16 + r;
        Hout[(size_t)row * N + col] = (bf16)gelu_f(acc[mf][nf][r] + bv[nf]);
      }
    }
}

// ---------------- 4-phase pipelined GEMM2 (unchanged, measured-good) --------
// MODE 1: dense, Fout[row] += gate[row*8+gidx]*(C+b)
// MODE 2: dense, Fout[row]  = gate[row*8+gidx]*(C+b)
// MODE 3: scatter, Fout[tok] += gate[tok*8+gidx]*(C+b)
template <int BN_, int MODE>
__global__ __launch_bounds__(512, 2) void gemm4p(
    const bf16* __restrict__ A, const bf16* __restrict__ B, int M, int N,
    int K, const float* __restrict__ bias, bf16* __restrict__ Hout,
    float* __restrict__ Fout, const float* __restrict__ gate, int gidx,
    int NBn, int CH_M, int CH_N, const int* __restrict__ cnt,
    const int* __restrict__ lists, int eid) {
  constexpr int NREP = BN_ / 64;
  constexpr int NHF = NREP / 2;
  constexpr int WNT = BN_ / 4;
  constexpr int ABYTES = 256 * 64 * 2;
  constexpr int BBYTES = BN_ * 64 * 2;
  constexpr bool DYN = (MODE == 3);

  __shared__ __align__(1024) bf16 Alds[2 * 256 * 64];
  __shared__ __align__(1024) bf16 Blds[2 * BN_ * 64];

  const int tid = threadIdx.x;
  const int lane = tid & 63, wid = tid >> 6;
  const int wm = wid >> 2, wn = wid & 3;
  const int lr = lane & 15, lg = lane >> 4;

  int bm, bn;
  if constexpr (DYN) {
    const int nbm = ((cnt[eid] + 255) & ~255) >> 8;
    const int CHm = (nbm + 3) >> 2;
    constexpr int CHn = (BN_ == 256) ? 8 : 4;
    const int need = 8 * CHm * CHn;
    if (blockIdx.x >= need) return;
    const int xc = blockIdx.x & 7;
    const int idx = blockIdx.x >> 3;
    bm = (xc >> 1) * CHm + idx / CHn;
    bn = (xc & 1) * CHn + idx % CHn;
    if (bm >= nbm) return;
  } else {
    const int xcd = blockIdx.x & 7;
    const int idx = blockIdx.x >> 3;
    const int ncn = NBn / CH_N;
    bm = (xcd / ncn) * CH_M + idx / CH_N;
    bn = (xcd % ncn) * CH_N + idx % CH_N;
  }

  const int NT = K >> 6;

  const int L = tid * 16;
  const int rl = L >> 7;
  const int colb = (L & 127) ^ ((rl & 7) << 4);

  const int ar0 = bm * 256 + rl;
  const bf16* sAc0 = A + (size_t)ar0 * K + (colb >> 1);
  const bf16* sAc1 = A + (size_t)(ar0 + 64) * K + (colb >> 1);
  const bf16* sAc2 = A + (size_t)(ar0 + 128) * K + (colb >> 1);
  const bf16* sAc3 = A + (size_t)(ar0 + 192) * K + (colb >> 1);
  const bf16* sB = B + (size_t)(bn * BN_ + rl) * K + (colb >> 1);

  char* const ldsA = (char*)Alds;
  char* const ldsB = (char*)Blds;
  const int wb = wid * 1024;
  char* const stA[2] = {ldsA + wb, ldsA + ABYTES + wb};
  char* const stB[2] = {ldsB + wb, ldsB + BBYTES + wb};

  const int ax0 = (lg * 16) ^ ((lr & 7) << 4);
  const int ax1 = ax0 ^ 64;
  const int aro = (wm * 128 + lr) * 128;
  const int bro = (wn * WNT + lr) * 128;
  const char* const Ak0[2] = {ldsA + aro + ax0, ldsA + ABYTES + aro + ax0};
  const char* const Ak1[2] = {ldsA + aro + ax1, ldsA + ABYTES + aro + ax1};
  const char* const Bk0[2] = {ldsB + bro + ax0, ldsB + BBYTES + bro + ax0};
  const char* const Bk1[2] = {ldsB + bro + ax1, ldsB + BBYTES + bro + ax1};

  f32x4 acc[8][NREP] = {};

  gl_lds16(sAc0, stA[0]);
  gl_lds16(sAc1, stA[0] + 8192);
  gl_lds16(sAc2, stA[0] + 16384);
  gl_lds16(sAc3, stA[0] + 24576);
  gl_lds16(sB, stB[0]);
  gl_lds16(sB + (size_t)64 * K, stB[0] + 8192);
  if constexpr (BN_ == 256) {
    gl_lds16(sB + (size_t)128 * K, stB[0] + 16384);
    gl_lds16(sB + (size_t)192 * K, stB[0] + 24576);
  }
  gl_lds16(sB + 64, stB[1]);
  gl_lds16(sB + (size_t)64 * K + 64, stB[1] + 8192);
  if constexpr (BN_ == 256) {
    gl_lds16(sB + (size_t)128 * K + 64, stB[1] + 16384);
    gl_lds16(sB + (size_t)192 * K + 64, stB[1] + 24576);
  }
  gl_lds16(sAc0 + 64, stA[1]);
  gl_lds16(sAc1 + 64, stA[1] + 8192);
  if constexpr (BN_ == 256) ASM_VMCNT(6); else ASM_VMCNT(4);
  __builtin_amdgcn_s_barrier();

  for (int kt0 = 0; kt0 < NT; kt0 += 2) {
#pragma unroll
    for (int par = 0; par < 2; ++par) {
      const int kt = kt0 + par;
      const int cur = par, oth = par ^ 1;
      const bool st1 = (kt + 1) < NT, st2 = (kt + 2) < NT;
      const size_t ko1 = (size_t)(kt + 1) << 6, ko2 = (size_t)(kt + 2) << 6;
      const char* Ac0 = Ak0[cur]; const char* Ac1 = Ak1[cur];
      const char* Bc0 = Bk0[cur]; const char* Bc1 = Bk1[cur];

      bf16x8 af[4][2], bfr[NREP][2];

#pragma unroll
      for (int mf = 0; mf < 4; ++mf) {
        af[mf][0] = *(const bf16x8*)(Ac0 + mf * 2048);
        af[mf][1] = *(const bf16x8*)(Ac1 + mf * 2048);
      }
#pragma unroll
      for (int nf = 0; nf < NHF; ++nf) {
        bfr[nf][0] = *(const bf16x8*)(Bc0 + nf * 2048);
        bfr[nf][1] = *(const bf16x8*)(Bc1 + nf * 2048);
      }
      if (st1) {
        gl_lds16(sAc2 + ko1, stA[oth] + 16384);
        gl_lds16(sAc3 + ko1, stA[oth] + 24576);
      }
      __builtin_amdgcn_s_barrier();
      asm volatile("s_waitcnt lgkmcnt(0)" ::: "memory");
      __builtin_amdgcn_sched_barrier(0);
      __builtin_amdgcn_s_setprio(1);
#pragma unroll
      for (int mf = 0; mf < 4; ++mf)
#pragma unroll
        for (int nf = 0; nf < NHF; ++nf) {
          acc[mf][nf] = MFMA16(af[mf][0], bfr[nf][0], acc[mf][nf]);
          acc[mf][nf] = MFMA16(af[mf][1], bfr[nf][1], acc[mf][nf]);
        }
      __builtin_amdgcn_s_setprio(0);
      __builtin_amdgcn_s_barrier();

#pragma unroll
      for (int nf = NHF; nf < NREP; ++nf) {
        bfr[nf][0] = *(const bf16x8*)(Bc0 + nf * 2048);
        bfr[nf][1] = *(const bf16x8*)(Bc1 + nf * 2048);
      }
      __builtin_amdgcn_s_barrier();
      asm volatile("s_waitcnt lgkmcnt(0)" ::: "memory");
      __builtin_amdgcn_sched_barrier(0);
      __builtin_amdgcn_s_setprio(1);
#pragma unroll
      for (int mf = 0; mf < 4; ++mf)
#pragma unroll
        for (int nf = NHF; nf < NREP; ++nf) {
          acc[mf][nf] = MFMA16(af[mf][0], bfr[nf][0], acc[mf][nf]);
          acc[mf][nf] = MFMA16(af[mf][1], bfr[nf][1], acc[mf][nf]);
        }
      __builtin_amdgcn_s_setprio(0);
      __builtin_amdgcn_s_barrier();

#pragma unroll
      for (int mf = 0; mf < 4; ++mf) {
        af[mf][0] = *(const bf16x8*)(Ac0 + 8192 + mf * 2048);
        af[mf][1] = *(const bf16x8*)(Ac1 + 8192 + mf * 2048);
      }
      if (st2) {
        gl_lds16(sB + ko2, stB[cur]);
        gl_lds16(sB + (size_t)64 * K + ko2, stB[cur] + 8192);
      }
      __builtin_amdgcn_s_barrier();
      asm volatile("s_waitcnt lgkmcnt(0)" ::: "memory");
      __builtin_amdgcn_sched_barrier(0);
      __builtin_amdgcn_s_setprio(1);
#pragma unroll
      for (int mf = 0; mf < 4; ++mf)
#pragma unroll
        for (int nf = 0; nf < NHF; ++nf) {
          acc[4 + mf][nf] = MFMA16(af[mf][0], bfr[nf][0], acc[4 + mf][nf]);
          acc[4 + mf][nf] = MFMA16(af[mf][1], bfr[nf][1], acc[4 + mf][nf]);
        }
      __builtin_amdgcn_s_setprio(0);
      __builtin_amdgcn_s_barrier();

      if (st2) {
        if constexpr (BN_ == 256) {
          gl_lds16(sB + (size_t)128 * K + ko2, stB[cur] + 16384);
          gl_lds16(sB + (size_t)192 * K + ko2, stB[cur] + 24576);
        }
        gl_lds16(sAc0 + ko2, stA[cur]);
        gl_lds16(sAc1 + ko2, stA[cur] + 8192);
      }
      __builtin_amdgcn_s_setprio(1);
#pragma unroll
      for (int mf = 0; mf < 4; ++mf)
#pragma unroll
        for (int nf = NHF; nf < NREP; ++nf) {
          acc[4 + mf][nf] = MFMA16(af[mf][0], bfr[nf][0], acc[4 + mf][nf]);
          acc[4 + mf][nf] = MFMA16(af[mf][1], bfr[nf][1], acc[4 + mf][nf]);
        }
      __builtin_amdgcn_s_setprio(0);
      if (st2) {
        if constexpr (BN_ == 256) ASM_VMCNT(6); else ASM_VMCNT(4);
        __builtin_amdgcn_s_barrier();
      } else if (st1) {
        ASM_VMCNT(0);
        __builtin_amdgcn_s_barrier();
      }
    }
  }

  const int colb2 = bn * BN_ + wn * WNT;
  const int rowb = bm * 256 + wm * 128 + lg * 4;
  float bv[NREP];
#pragma unroll
  for (int nf = 0; nf < NREP; ++nf) bv[nf] = bias[colb2 + nf * 16 + lr];
#pragma unroll
  for (int mf = 0; mf < 8; ++mf) {
    if constexpr (MODE == 1 || MODE == 2) {
      float gv[4];
#pragma unroll
      for (int r = 0; r < 4; ++r)
        gv[r] = gate[(size_t)(rowb + mf * 16 + r) * 8 + gidx];
#pragma unroll
      for (int nf = 0; nf < NREP; ++nf) {
        const int col = colb2 + nf * 16 + lr;
#pragma unroll
        for (int r = 0; r < 4; ++r) {
          const float v = acc[mf][nf][r] + bv[nf];
          const size_t oi = (size_t)(rowb + mf * 16 + r) * N + col;
          if constexpr (MODE == 1)
            Fout[oi] += gv[r] * v;
          else
            Fout[oi] = gv[r] * v;
        }
      }
    } else {  // MODE 3: scatter-add via token list
      const int* lp = lists + eid * 8192;
      int tok[4]; float gv[4];
#pragma unroll
      for (int r = 0; r < 4; ++r) {
        tok[r] = lp[rowb + mf * 16 + r];
        gv[r] = tok[r] >= 0 ? gate[(size_t)tok[r] * 8 + gidx] : 0.0f;
      }
#pragma unroll
      for (int nf = 0; nf < NREP; ++nf) {
        const int col = colb2 + nf * 16 + lr;
#pragma unroll
        for (int r = 0; r < 4; ++r) {
          if (tok[r] >= 0) {
            const float v = acc[mf][nf][r] + bv[nf];
            Fout[(size_t)tok[r] * N + col] += gv[r] * v;
          }
        }
      }
    }
  }
}

extern "C" void kernel_launch(void* const* d_in, const int* in_sizes, int n_in,
                              void* d_out, int out_size, void* d_ws,
                              size_t ws_size, hipStream_t stream) {
  const float* x = (const float*)d_in[0];
  const float* spec_w1 = (const float*)d_in[1];
  const float* spec_b1 = (const float*)d_in[2];
  const float* spec_w2 = (const float*)d_in[3];
  const float* spec_b2 = (const float*)d_in[4];
  const float* spec_rw = (const float*)d_in[5];
  const float* spec_rb = (const float*)d_in[6];
  const float* shr_w1 = (const float*)d_in[7];
  const float* shr_b1 = (const float*)d_in[8];
  const float* shr_w2 = (const float*)d_in[9];
  const float* shr_b2 = (const float*)d_in[10];
  const float* shr_rw = (const float*)d_in[11];
  const float* shr_rb = (const float*)d_in[12];
  float* out = (float*)d_out;

  char* ws = (char*)d_ws;
  const size_t OFF_W1 = 16777216;            // xb: 16 MB
  const size_t OFF_W2 = OFF_W1 + 50331648;   // w1t: 48 MB
  const size_t OFF_H = OFF_W2 + 50331648;    // w2t: 48 MB
  const size_t OFF_GATE = OFF_H + 67108864;  // hbuf: 64 MB
  const size_t OFF_AUX = OFF_GATE + 262144;
  const size_t OFF_CNT = OFF_AUX + 64;
  const size_t OFF_LIST = OFF_CNT + 64;
  const size_t OFF_T2 = OFF_LIST + 131072;
  const size_t OFF_P4 = OFF_T2 + 32768;
  bf16* xb = (bf16*)ws;
  bf16* w1t = (bf16*)(ws + OFF_W1);
  bf16* w2t = (bf16*)(ws + OFF_W2);
  bf16* hbuf = (bf16*)(ws + OFF_H);
  float* gate = (float*)(ws + OFF_GATE);
  float* auxg = (float*)(ws + OFF_AUX);
  int* cnt = (int*)(ws + OFF_CNT);
  int* lists = (int*)(ws + OFF_LIST);
  int* top2 = (int*)(ws + OFF_T2);
  float4* probs4 = (float4*)(ws + OFF_P4);

  hipMemsetAsync(lists, 0xFF, 4 * 8192 * 4, stream);  // -1 sentinel

  convert_x<<<(T_TOK * DDIM) / 2048, 256, 0, stream>>>(x, xb);
  transpose_convert<<<dim3(HDIM / 32, DDIM / 32, 4), 256, 0, stream>>>(
      spec_w1, w1t, DDIM, HDIM);
  transpose_convert<<<dim3(HDIM / 32, DDIM / 32, 2), 256, 0, stream>>>(
      shr_w1, w1t + (size_t)4 * DDIM * HDIM, DDIM, HDIM);
  transpose_convert<<<dim3(DDIM / 32, HDIM / 32, 4), 256, 0, stream>>>(
      spec_w2, w2t, HDIM, DDIM);
  transpose_convert<<<dim3(DDIM / 32, HDIM / 32, 2), 256, 0, stream>>>(
      shr_w2, w2t + (size_t)4 * DDIM * HDIM, HDIM, DDIM);

  router_probs<<<T_TOK / 4, 256, 0, stream>>>(x, spec_rw, spec_rb, shr_rw,
                                              shr_rb, gate, probs4, top2);
  scan_build<<<1, 1024, 0, stream>>>(top2, probs4, cnt, lists, auxg);

  // ---- shared experts: dense over all tokens (e0 writes, e1 accumulates) ----
  for (int es = 0; es < 2; ++es) {
    const bf16* w1e = w1t + (size_t)(4 + es) * DDIM * HDIM;
    const bf16* w2e = w2t + (size_t)(4 + es) * DDIM * HDIM;
    const float* b1e = shr_b1 + (size_t)es * HDIM;
    const float* b2e = shr_b2 + (size_t)es * DDIM;
    gemmv<0><<<2048, 256, 0, stream>>>(xb, w1e, HDIM, DDIM, b1e, hbuf,
                                       32, 16, 16, nullptr, nullptr, 0);
    if (es == 0)
      gemm4p<128, 2><<<256, 512, 0, stream>>>(
          hbuf, w2e, T_TOK, DDIM, HDIM, b2e, nullptr, out, gate, 4,
          8, 8, 4, nullptr, nullptr, 0);
    else
      gemm4p<128, 1><<<256, 512, 0, stream>>>(
          hbuf, w2e, T_TOK, DDIM, HDIM, b2e, nullptr, out, gate, 5,
          8, 8, 4, nullptr, nullptr, 0);
  }

  // ---- specific experts: top-2 sparse (gather-on-stage, scatter-add) ----
  for (int e = 0; e < 4; ++e) {
    const bf16* w1e = w1t + (size_t)e * DDIM * HDIM;
    const bf16* w2e = w2t + (size_t)e * DDIM * HDIM;
    const float* b1e = spec_b1 + (size_t)e * HDIM;
    const float* b2e = spec_b2 + (size_t)e * DDIM;
    gemmv<4><<<2048, 256, 0, stream>>>(xb, w1e, HDIM, DDIM, b1e, hbuf,
                                       32, 0, 16, cnt, lists, e);
    gemm4p<128, 3><<<256, 512, 0, stream>>>(
        hbuf, w2e, T_TOK, DDIM, HDIM, b2e, nullptr, out, gate, e,
        8, 0, 0, cnt, lists, e);
  }
  aux_finalize<<<1, 1, 0, stream>>>(auxg, out + (size_t)T_TOK * DDIM);
}